// Round 2
// baseline (996.786 us; speedup 1.0000x reference)
//
#include <hip/hip_runtime.h>
#include <cstdint>
#include <cstddef>

typedef unsigned short u16;
typedef unsigned int   u32;
typedef __attribute__((ext_vector_type(8))) short short8;   // 8 bf16 (4 VGPRs) MFMA A/B frag
typedef __attribute__((ext_vector_type(4))) float f32x4;    // MFMA C/D frag

// ---------- bf16 helpers (round-to-nearest-even) ----------
__device__ __forceinline__ u16 f2bf(float f) {
    union { float f; u32 u; } v; v.f = f;
    u32 r = v.u + 0x7fffu + ((v.u >> 16) & 1u);
    return (u16)(r >> 16);
}
__device__ __forceinline__ float bf2f(u16 b) {
    union { u32 u; float f; } v; v.u = ((u32)b) << 16;
    return v.f;
}

// ---------- constants ----------
#define SEQ   4096
#define BATCH 2
#define NH    8
#define DKH   128
#define DVH   256
#define DMODEL 1024
#define NPROJ 6144          // q(1024) | k(1024) | v(2048) | og(2048)
#define CHUNK 64
#define NCHUNK (SEQ / CHUNK)  // 64

// ws layout (byte offsets)
#define OFF_XB    0u                 // x bf16              [8192][1024]    16,777,216
#define OFF_WCAT  16777216u          // WcatT bf16          [6144][1024]    12,582,912
#define OFF_WOT   29360128u          // WoT bf16            [1024][2048]     4,194,304
#define OFF_PROJ  33554432u          // proj bf16           [8192][6144]   100,663,296
#define OFF_L2A   134217728u         // log2(alpha) f32     [8192][8]          262,144
#define OFF_GC    134479872u         // per-chunk decay f32 [16][64]             4,096
#define OFF_U     134483968u         // U / S_prefix bf16   [16][64][256][128] 67,108,864
#define OFF_Z     201592832u         // z = o*og bf16       [8192][2048]    33,554,432
// total 235,147,264 bytes

// ---------- f32 -> bf16 convert (x) ----------
__global__ __launch_bounds__(256) void cvt_x_kernel(const float* __restrict__ x,
                                                    u16* __restrict__ xb) {
    int i = (blockIdx.x * 256 + threadIdx.x) * 4;
    float4 v = *(const float4*)(x + i);
    u16 o[4] = { f2bf(v.x), f2bf(v.y), f2bf(v.z), f2bf(v.w) };
    *(uint2*)(xb + i) = *(const uint2*)o;
}

// ---------- weight transpose + bf16 (out[n][k] = W[k][n] * scale) ----------
__global__ __launch_bounds__(256) void transpose_w(const float* __restrict__ W, int N, int K,
                                                   u16* __restrict__ outp, float scale) {
    __shared__ float t[32][33];
    int n0 = blockIdx.x * 32, k0 = blockIdx.y * 32;
    int tx = threadIdx.x, ty = threadIdx.y;
    #pragma unroll
    for (int j = 0; j < 4; ++j)
        t[ty + j * 8][tx] = W[(size_t)(k0 + ty + j * 8) * N + n0 + tx];
    __syncthreads();
    #pragma unroll
    for (int j = 0; j < 4; ++j)
        outp[(size_t)(n0 + ty + j * 8) * K + k0 + tx] = f2bf(t[tx][ty + j * 8] * scale);
}

// ---------- gate kernel: l2a = log2(sigmoid((x@Wg + bg)/16)), pure f32 ----------
__global__ __launch_bounds__(256) void alpha_kernel(const float* __restrict__ x,
                                                    const float* __restrict__ Wg,
                                                    const float* __restrict__ bg,
                                                    float* __restrict__ l2a) {
    __shared__ float xr[DMODEL];
    int row = blockIdx.x;
    for (int i = threadIdx.x; i < DMODEL; i += 256) xr[i] = x[(size_t)row * DMODEL + i];
    __syncthreads();
    int wave = threadIdx.x >> 6, lane = threadIdx.x & 63;
    #pragma unroll
    for (int hh = 0; hh < 2; ++hh) {
        int h = wave * 2 + hh;
        float p = 0.f;
        for (int i = lane; i < DMODEL; i += 64) p += xr[i] * Wg[i * NH + h];
        #pragma unroll
        for (int d = 32; d; d >>= 1) p += __shfl_down(p, d, 64);
        if (lane == 0) {
            float zz = (p + bg[h]) * (1.0f / 16.0f);
            float a = 1.0f / (1.0f + expf(-zz));
            l2a[row * NH + h] = log2f(a);
        }
    }
}

// ---------- 128x128 bf16 MFMA GEMM: C[M,N] = A[M,K] @ B[N,K]^T ----------
// EPI=1: bf16 out, sigmoid for n >= og_start.  EPI=0: f32 out.
template <int EPI>
__global__ __launch_bounds__(256) void gemm128(const u16* __restrict__ A, int lda,
                                               const u16* __restrict__ B, int ldb,
                                               void* __restrict__ Cout, int ldc,
                                               int K, int og_start) {
    __shared__ u16 As[128 * 40];
    __shared__ u16 Bs[128 * 40];
    const int tid = threadIdx.x;
    const int lane = tid & 63, wave = tid >> 6;
    const int m0 = blockIdx.y * 128, n0 = blockIdx.x * 128;
    const int m_off = (wave & 1) * 64, n_off = (wave >> 1) * 64;
    f32x4 acc[4][4] = {};
    for (int k0 = 0; k0 < K; k0 += 32) {
        uint4 av[2], bv[2];
        #pragma unroll
        for (int j = 0; j < 2; ++j) {
            int cid = tid + j * 256;
            int r = cid >> 2, koff = (cid & 3) * 8;
            av[j] = *(const uint4*)(A + (size_t)(m0 + r) * lda + k0 + koff);
            bv[j] = *(const uint4*)(B + (size_t)(n0 + r) * ldb + k0 + koff);
        }
        __syncthreads();
        #pragma unroll
        for (int j = 0; j < 2; ++j) {
            int cid = tid + j * 256;
            int r = cid >> 2, koff = (cid & 3) * 8;
            *reinterpret_cast<uint4*>(&As[r * 40 + koff]) = av[j];
            *reinterpret_cast<uint4*>(&Bs[r * 40 + koff]) = bv[j];
        }
        __syncthreads();
        short8 a[4], b[4];
        #pragma unroll
        for (int rt = 0; rt < 4; ++rt)
            a[rt] = *reinterpret_cast<const short8*>(&As[(m_off + rt * 16 + (lane & 15)) * 40 + (lane >> 4) * 8]);
        #pragma unroll
        for (int ct = 0; ct < 4; ++ct)
            b[ct] = *reinterpret_cast<const short8*>(&Bs[(n_off + ct * 16 + (lane & 15)) * 40 + (lane >> 4) * 8]);
        #pragma unroll
        for (int rt = 0; rt < 4; ++rt)
            #pragma unroll
            for (int ct = 0; ct < 4; ++ct)
                acc[rt][ct] = __builtin_amdgcn_mfma_f32_16x16x32_bf16(a[rt], b[ct], acc[rt][ct], 0, 0, 0);
    }
    #pragma unroll
    for (int rt = 0; rt < 4; ++rt)
        #pragma unroll
        for (int ct = 0; ct < 4; ++ct)
            #pragma unroll
            for (int j = 0; j < 4; ++j) {
                int m = m0 + m_off + rt * 16 + (lane >> 4) * 4 + j;
                int n = n0 + n_off + ct * 16 + (lane & 15);
                float v = acc[rt][ct][j];
                if (EPI) {
                    if (n >= og_start) v = 1.0f / (1.0f + expf(-v));
                    ((u16*)Cout)[(size_t)m * ldc + n] = f2bf(v);
                } else {
                    ((float*)Cout)[(size_t)m * ldc + n] = v;
                }
            }
}

// ---------- R1: per-chunk U^T = (v .* w)^T-layout MFMA ----------
// U stored [bh][chunk][c(256)][r(128)] bf16 (i.e. U^T); Gc = chunk total decay.
__global__ __launch_bounds__(256) void r1_kernel(const u16* __restrict__ proj,
                                                 const float* __restrict__ l2a,
                                                 u16* __restrict__ U,
                                                 float* __restrict__ Gc) {
    __shared__ u16 kT[128 * 72];   // kT[r][s]
    __shared__ u16 vT[256 * 72];   // vT[c][s], scaled by w_s
    __shared__ float Wsh[64];
    int bid = blockIdx.x;
    int c = bid & 63, bh = bid >> 6;
    int b = bh >> 3, h = bh & 7;
    int c0 = c * CHUNK;
    int tid = threadIdx.x, lane = tid & 63, wave = tid >> 6;
    size_t rowbase = (size_t)b * SEQ + c0;
    if (wave == 0) {
        float L = l2a[(rowbase + lane) * NH + h];
        #pragma unroll
        for (int d = 1; d < 64; d <<= 1) {
            float u = __shfl_up(L, d, 64);
            if (lane >= d) L += u;
        }
        float Lend = __shfl(L, 63, 64);
        Wsh[lane] = exp2f(Lend - L);
        if (lane == 0) Gc[bh * NCHUNK + c] = exp2f(Lend);
    }
    __syncthreads();
    // stage kT (transpose in LDS)
    #pragma unroll
    for (int j = 0; j < 4; ++j) {
        int cid = tid + j * 256;
        int s = cid >> 4, r = (cid & 15) * 8;
        uint4 v = *(const uint4*)(proj + (rowbase + s) * NPROJ + 1024 + h * DKH + r);
        u16 e[8]; *(uint4*)e = v;
        #pragma unroll
        for (int i = 0; i < 8; ++i) kT[(r + i) * 72 + s] = e[i];
    }
    // stage vT scaled by w_s
    #pragma unroll
    for (int j = 0; j < 8; ++j) {
        int cid = tid + j * 256;
        int s = cid >> 5, cc = (cid & 31) * 8;
        float w = Wsh[s];
        uint4 v = *(const uint4*)(proj + (rowbase + s) * NPROJ + 2048 + h * DVH + cc);
        u16 e[8]; *(uint4*)e = v;
        #pragma unroll
        for (int i = 0; i < 8; ++i) vT[(cc + i) * 72 + s] = f2bf(bf2f(e[i]) * w);
    }
    __syncthreads();
    // U^T[c][r] = sum_s (w_s v[s][c]) k[s][r]; wave owns c-rows [64*wave, +64)
    short8 afr[4][2];
    #pragma unroll
    for (int rt = 0; rt < 4; ++rt)
        #pragma unroll
        for (int kk = 0; kk < 2; ++kk)
            afr[rt][kk] = *reinterpret_cast<const short8*>(
                &vT[(wave * 64 + rt * 16 + (lane & 15)) * 72 + kk * 32 + (lane >> 4) * 8]);
    size_t ubase = (size_t)(bh * NCHUNK + c) * (DVH * DKH);
    #pragma unroll
    for (int ct = 0; ct < 8; ++ct) {
        f32x4 acc[4] = {};
        #pragma unroll
        for (int kk = 0; kk < 2; ++kk) {
            short8 bfr = *reinterpret_cast<const short8*>(
                &kT[(ct * 16 + (lane & 15)) * 72 + kk * 32 + (lane >> 4) * 8]);
            #pragma unroll
            for (int rt = 0; rt < 4; ++rt)
                acc[rt] = __builtin_amdgcn_mfma_f32_16x16x32_bf16(afr[rt][kk], bfr, acc[rt], 0, 0, 0);
        }
        #pragma unroll
        for (int rt = 0; rt < 4; ++rt)
            #pragma unroll
            for (int j = 0; j < 4; ++j) {
                int ccr = wave * 64 + rt * 16 + (lane >> 4) * 4 + j;
                int rr = ct * 16 + (lane & 15);
                U[ubase + (size_t)ccr * DKH + rr] = f2bf(acc[rt][j]);
            }
    }
}

// ---------- R2: sequential scan over chunks (in-place U -> S_prefix) ----------
__global__ __launch_bounds__(256) void r2_kernel(u16* __restrict__ U, const float* __restrict__ Gc) {
    int bh = blockIdx.x >> 5;
    int e0 = ((blockIdx.x & 31) * 256 + threadIdx.x) * 4;
    const float* g = Gc + bh * NCHUNK;
    size_t base = (size_t)bh * NCHUNK * (DVH * DKH) + e0;
    float s0 = 0.f, s1 = 0.f, s2 = 0.f, s3 = 0.f;
    for (int c = 0; c < NCHUNK; ++c) {
        u16* p = U + base + (size_t)c * (DVH * DKH);
        uint2 u = *(const uint2*)p;
        u16 e[4]; *(uint2*)e = u;
        u16 o[4] = { f2bf(s0), f2bf(s1), f2bf(s2), f2bf(s3) };
        *(uint2*)p = *(const uint2*)o;          // write S_prefix[c]
        float G = g[c];
        s0 = G * s0 + bf2f(e[0]);
        s1 = G * s1 + bf2f(e[1]);
        s2 = G * s2 + bf2f(e[2]);
        s3 = G * s3 + bf2f(e[3]);
    }
}

// ---------- R3: chunk outputs (inter + intra) fused with og multiply ----------
__global__ __launch_bounds__(256) void r3_kernel(const u16* __restrict__ proj,
                                                 const u16* __restrict__ Sp,
                                                 const float* __restrict__ l2a,
                                                 u16* __restrict__ z) {
    __shared__ u16 vT[256 * 72];   // vT[c][s]
    __shared__ u16 P[64 * 72];     // P[t][s] decayed, bf16
    __shared__ float Lsh[64];
    int bid = blockIdx.x;
    int c = bid & 63, bh = bid >> 6;
    int b = bh >> 3, h = bh & 7;
    int c0 = c * CHUNK;
    int tid = threadIdx.x, lane = tid & 63, wave = tid >> 6;
    size_t rowbase = (size_t)b * SEQ + c0;
    if (wave == 0) {
        float L = l2a[(rowbase + lane) * NH + h];
        #pragma unroll
        for (int d = 1; d < 64; d <<= 1) {
            float u = __shfl_up(L, d, 64);
            if (lane >= d) L += u;
        }
        Lsh[lane] = L;
    }
    // stage vT (unscaled)
    #pragma unroll
    for (int j = 0; j < 8; ++j) {
        int cid = tid + j * 256;
        int s = cid >> 5, cc = (cid & 31) * 8;
        uint4 v = *(const uint4*)(proj + (rowbase + s) * NPROJ + 2048 + h * DVH + cc);
        u16 e[8]; *(uint4*)e = v;
        #pragma unroll
        for (int i = 0; i < 8; ++i) vT[(cc + i) * 72 + s] = e[i];
    }
    __syncthreads();
    // phase 1a: P strip rows [16*wave, +16): P[t][s] = (q k^T)[t][s] * exp2(L_t - L_s), causal
    {
        f32x4 pacc[4] = {};
        #pragma unroll
        for (int kk = 0; kk < 4; ++kk) {
            short8 a = *reinterpret_cast<const short8*>(
                proj + (rowbase + wave * 16 + (lane & 15)) * NPROJ + h * DKH + kk * 32 + (lane >> 4) * 8);
            #pragma unroll
            for (int st = 0; st < 4; ++st) {
                short8 bb = *reinterpret_cast<const short8*>(
                    proj + (rowbase + st * 16 + (lane & 15)) * NPROJ + 1024 + h * DKH + kk * 32 + (lane >> 4) * 8);
                pacc[st] = __builtin_amdgcn_mfma_f32_16x16x32_bf16(a, bb, pacc[st], 0, 0, 0);
            }
        }
        #pragma unroll
        for (int st = 0; st < 4; ++st)
            #pragma unroll
            for (int j = 0; j < 4; ++j) {
                int t = wave * 16 + (lane >> 4) * 4 + j;
                int s = st * 16 + (lane & 15);
                float val = pacc[st][j];
                val = (s <= t) ? val * exp2f(Lsh[t] - Lsh[s]) : 0.f;
                P[t * 72 + s] = f2bf(val);
            }
    }
    // phase 1b: inter = q @ S_prefix (wave owns output cols [64*wave, +64))
    f32x4 acc[4][4] = {};
    size_t spbase = (size_t)(bh * NCHUNK + c) * (DVH * DKH);
    #pragma unroll
    for (int kk = 0; kk < 4; ++kk) {
        short8 a[4];
        #pragma unroll
        for (int rt = 0; rt < 4; ++rt)
            a[rt] = *reinterpret_cast<const short8*>(
                proj + (rowbase + rt * 16 + (lane & 15)) * NPROJ + h * DKH + kk * 32 + (lane >> 4) * 8);
        #pragma unroll
        for (int ct = 0; ct < 4; ++ct) {
            short8 bb = *reinterpret_cast<const short8*>(
                Sp + spbase + (size_t)(wave * 64 + ct * 16 + (lane & 15)) * DKH + kk * 32 + (lane >> 4) * 8);
            #pragma unroll
            for (int rt = 0; rt < 4; ++rt)
                acc[rt][ct] = __builtin_amdgcn_mfma_f32_16x16x32_bf16(a[rt], bb, acc[rt][ct], 0, 0, 0);
        }
    }
    // scale inter by A_t = exp2(L_t)
    #pragma unroll
    for (int rt = 0; rt < 4; ++rt)
        #pragma unroll
        for (int j = 0; j < 4; ++j) {
            float at = exp2f(Lsh[rt * 16 + (lane >> 4) * 4 + j]);
            #pragma unroll
            for (int ct = 0; ct < 4; ++ct) acc[rt][ct][j] *= at;
        }
    __syncthreads();
    // phase 2: intra = P @ v
    #pragma unroll
    for (int kk = 0; kk < 2; ++kk) {
        short8 pa[4];
        #pragma unroll
        for (int rt = 0; rt < 4; ++rt)
            pa[rt] = *reinterpret_cast<const short8*>(&P[(rt * 16 + (lane & 15)) * 72 + kk * 32 + (lane >> 4) * 8]);
        #pragma unroll
        for (int ct = 0; ct < 4; ++ct) {
            short8 vb = *reinterpret_cast<const short8*>(
                &vT[(wave * 64 + ct * 16 + (lane & 15)) * 72 + kk * 32 + (lane >> 4) * 8]);
            #pragma unroll
            for (int rt = 0; rt < 4; ++rt)
                acc[rt][ct] = __builtin_amdgcn_mfma_f32_16x16x32_bf16(pa[rt], vb, acc[rt][ct], 0, 0, 0);
        }
    }
    // phase 3: z = o * og
    #pragma unroll
    for (int rt = 0; rt < 4; ++rt)
        #pragma unroll
        for (int ct = 0; ct < 4; ++ct)
            #pragma unroll
            for (int j = 0; j < 4; ++j) {
                int t = rt * 16 + (lane >> 4) * 4 + j;
                int cc = wave * 64 + ct * 16 + (lane & 15);
                float og = bf2f(proj[(rowbase + t) * NPROJ + 4096 + h * DVH + cc]);
                float v = acc[rt][ct][j] * og;
                z[(rowbase + t) * (NH * DVH) + h * DVH + cc] = f2bf(v);
            }
}

extern "C" void kernel_launch(void* const* d_in, const int* in_sizes, int n_in,
                              void* d_out, int out_size, void* d_ws, size_t ws_size,
                              hipStream_t stream) {
    const float* x   = (const float*)d_in[0];
    const float* Wq  = (const float*)d_in[1];
    const float* Wk  = (const float*)d_in[2];
    const float* Wv  = (const float*)d_in[3];
    const float* Wo  = (const float*)d_in[4];
    const float* Wg  = (const float*)d_in[5];
    const float* bg  = (const float*)d_in[6];
    const float* Wog = (const float*)d_in[7];
    float* out = (float*)d_out;
    char* ws = (char*)d_ws;

    u16*   xb   = (u16*)(ws + OFF_XB);
    u16*   wcat = (u16*)(ws + OFF_WCAT);
    u16*   wot  = (u16*)(ws + OFF_WOT);
    u16*   proj = (u16*)(ws + OFF_PROJ);
    float* l2a  = (float*)(ws + OFF_L2A);
    float* gc   = (float*)(ws + OFF_GC);
    u16*   U    = (u16*)(ws + OFF_U);
    u16*   z    = (u16*)(ws + OFF_Z);

    cvt_x_kernel<<<8192, 256, 0, stream>>>(x, xb);
    dim3 tb(32, 8);
    transpose_w<<<dim3(32, 32), tb, 0, stream>>>(Wq,  1024, 1024, wcat,               1.0f);
    transpose_w<<<dim3(32, 32), tb, 0, stream>>>(Wk,  1024, 1024, wcat + 1024 * 1024, 0.08838834764831845f); // fold DK^-0.5
    transpose_w<<<dim3(64, 32), tb, 0, stream>>>(Wv,  2048, 1024, wcat + 2048 * 1024, 1.0f);
    transpose_w<<<dim3(64, 32), tb, 0, stream>>>(Wog, 2048, 1024, wcat + 4096 * 1024, 1.0f);
    transpose_w<<<dim3(32, 64), tb, 0, stream>>>(Wo,  1024, 2048, wot,                1.0f);
    alpha_kernel<<<8192, 256, 0, stream>>>(x, Wg, bg, l2a);
    // projections: [8192,1024] @ [6144,1024]^T -> proj bf16 (sigmoid on og cols)
    gemm128<1><<<dim3(48, 64), 256, 0, stream>>>(xb, 1024, wcat, 1024, proj, NPROJ, 1024, 4096);
    r1_kernel<<<BATCH * NH * NCHUNK, 256, 0, stream>>>(proj, l2a, U, gc);
    r2_kernel<<<512, 256, 0, stream>>>(U, gc);
    r3_kernel<<<BATCH * NH * NCHUNK, 256, 0, stream>>>(proj, U, l2a, z);
    // final: [8192,2048] @ [1024,2048]^T -> d_out f32
    gemm128<0><<<dim3(8, 64), 256, 0, stream>>>(z, 2048, wot, 2048, out, 1024, 2048, 1 << 30);
}

// Round 3
// 607.963 us; speedup vs baseline: 1.6395x; 1.6395x over previous
//
#include <hip/hip_runtime.h>
#include <cstdint>
#include <cstddef>

typedef unsigned short u16;
typedef unsigned int   u32;
typedef __attribute__((ext_vector_type(8))) short short8;   // 8 bf16 (4 VGPRs) MFMA A/B frag
typedef __attribute__((ext_vector_type(4))) float f32x4;    // MFMA C/D frag

// ---------- bf16 helpers (round-to-nearest-even) ----------
__device__ __forceinline__ u16 f2bf(float f) {
    union { float f; u32 u; } v; v.f = f;
    u32 r = v.u + 0x7fffu + ((v.u >> 16) & 1u);
    return (u16)(r >> 16);
}
__device__ __forceinline__ float bf2f(u16 b) {
    union { u32 u; float f; } v; v.u = ((u32)b) << 16;
    return v.f;
}

// async global->LDS, 16B per lane. HW: lds dest = wave-uniform base + lane*16.
__device__ __forceinline__ void gload16(const u16* g, u16* l) {
    __builtin_amdgcn_global_load_lds(
        (const __attribute__((address_space(1))) u32*)g,
        (__attribute__((address_space(3))) u32*)l,
        16, 0, 0);
}

// ---------- constants ----------
#define SEQ   4096
#define BATCH 2
#define NH    8
#define DKH   128
#define DVH   256
#define DMODEL 1024
#define NPROJ 6144          // q(1024) | k(1024) | v(2048) | og(2048)
#define CHUNK 64
#define NCHUNK (SEQ / CHUNK)  // 64

// ws layout (byte offsets)
#define OFF_XB    0u                 // x bf16              [8192][1024]    16,777,216
#define OFF_WCAT  16777216u          // WcatT bf16          [6144][1024]    12,582,912
#define OFF_WOT   29360128u          // WoT bf16            [1024][2048]     4,194,304
#define OFF_PROJ  33554432u          // proj bf16           [8192][6144]   100,663,296
#define OFF_L2A   134217728u         // log2(alpha) f32     [8192][8]          262,144
#define OFF_GC    134479872u         // per-chunk decay f32 [16][64]             4,096
#define OFF_U     134483968u         // U / S_prefix bf16   [16][64][256][128] 67,108,864
#define OFF_Z     201592832u         // z = o*og bf16       [8192][2048]    33,554,432
// total 235,147,264 bytes

// ---------- f32 -> bf16 convert (x) ----------
__global__ __launch_bounds__(256) void cvt_x_kernel(const float* __restrict__ x,
                                                    u16* __restrict__ xb) {
    int i = (blockIdx.x * 256 + threadIdx.x) * 4;
    float4 v = *(const float4*)(x + i);
    u16 o[4] = { f2bf(v.x), f2bf(v.y), f2bf(v.z), f2bf(v.w) };
    *(uint2*)(xb + i) = *(const uint2*)o;
}

// ---------- weight transpose + bf16 (out[n][k] = W[k][n] * scale) ----------
__global__ __launch_bounds__(256) void transpose_w(const float* __restrict__ W, int N, int K,
                                                   u16* __restrict__ outp, float scale) {
    __shared__ float t[32][33];
    int n0 = blockIdx.x * 32, k0 = blockIdx.y * 32;
    int tx = threadIdx.x, ty = threadIdx.y;
    #pragma unroll
    for (int j = 0; j < 4; ++j)
        t[ty + j * 8][tx] = W[(size_t)(k0 + ty + j * 8) * N + n0 + tx];
    __syncthreads();
    #pragma unroll
    for (int j = 0; j < 4; ++j)
        outp[(size_t)(n0 + ty + j * 8) * K + k0 + tx] = f2bf(t[tx][ty + j * 8] * scale);
}

// ---------- gate kernel: l2a = log2(sigmoid((x@Wg + bg)/16)), pure f32 ----------
__global__ __launch_bounds__(256) void alpha_kernel(const float* __restrict__ x,
                                                    const float* __restrict__ Wg,
                                                    const float* __restrict__ bg,
                                                    float* __restrict__ l2a) {
    __shared__ float xr[DMODEL];
    int row = blockIdx.x;
    for (int i = threadIdx.x; i < DMODEL; i += 256) xr[i] = x[(size_t)row * DMODEL + i];
    __syncthreads();
    int wave = threadIdx.x >> 6, lane = threadIdx.x & 63;
    #pragma unroll
    for (int hh = 0; hh < 2; ++hh) {
        int h = wave * 2 + hh;
        float p = 0.f;
        for (int i = lane; i < DMODEL; i += 64) p += xr[i] * Wg[i * NH + h];
        #pragma unroll
        for (int d = 32; d; d >>= 1) p += __shfl_down(p, d, 64);
        if (lane == 0) {
            float zz = (p + bg[h]) * (1.0f / 16.0f);
            float a = 1.0f / (1.0f + expf(-zz));
            l2a[row * NH + h] = log2f(a);
        }
    }
}

// ---------- 128x128 bf16 MFMA GEMM, m97-style: C[M,N] = A[M,K] @ B[N,K]^T ----------
// BK=32, linear LDS (64B row stride), global_load_lds width-16 staging, 2-barrier loop.
// EPI=1: bf16 out via LDS-bounce coalesced stores, sigmoid for n >= og_start.
// EPI=0: f32 out, direct stores (already full-sector).
template <int EPI>
__global__ __launch_bounds__(256) void gemm_glds(const u16* __restrict__ A, int lda,
                                                 const u16* __restrict__ B, int ldb,
                                                 void* __restrict__ Cout, int ldc,
                                                 int K, int og_start) {
    __shared__ u16 smem[18432];          // 36 KB: staging (16KB) reused by epilogue (36KB)
    u16* As = smem;                      // [128][32] linear
    u16* Bs = smem + 4096;               // [128][32] linear
    const int tid = threadIdx.x;
    const int lane = tid & 63, wave = tid >> 6;
    const int m0 = blockIdx.y * 128, n0 = blockIdx.x * 128;
    const int m_off = (wave & 1) * 64, n_off = (wave >> 1) * 64;
    const int r = tid >> 2, kg = (tid & 3) * 8;     // staging: 4 lanes x 8 els cover a 32-el row
    f32x4 acc[4][4] = {};
    for (int k0 = 0; k0 < K; k0 += 32) {
        #pragma unroll
        for (int i = 0; i < 2; ++i) {
            int row = i * 64 + r;
            gload16(A + (size_t)(m0 + row) * lda + k0 + kg, As + (i * 256 + (tid & 192)) * 8);
            gload16(B + (size_t)(n0 + row) * ldb + k0 + kg, Bs + (i * 256 + (tid & 192)) * 8);
        }
        __syncthreads();                 // vmcnt(0) drain: tile ready
        short8 a[4], b[4];
        #pragma unroll
        for (int rt = 0; rt < 4; ++rt)
            a[rt] = *reinterpret_cast<const short8*>(&As[(m_off + rt * 16 + (lane & 15)) * 32 + (lane >> 4) * 8]);
        #pragma unroll
        for (int ct = 0; ct < 4; ++ct)
            b[ct] = *reinterpret_cast<const short8*>(&Bs[(n_off + ct * 16 + (lane & 15)) * 32 + (lane >> 4) * 8]);
        #pragma unroll
        for (int rt = 0; rt < 4; ++rt)
            #pragma unroll
            for (int ct = 0; ct < 4; ++ct)
                acc[rt][ct] = __builtin_amdgcn_mfma_f32_16x16x32_bf16(a[rt], b[ct], acc[rt][ct], 0, 0, 0);
        __syncthreads();                 // all reads done before next stage overwrites
    }
    if (EPI) {
        // LDS-bounce epilogue: per-wave 64x64 bf16 tile, stride 72 (bank-spread), then
        // uint4 read-back -> 128B-per-row coalesced global stores.
        u16* Cw = smem + wave * 4608;
        #pragma unroll
        for (int rt = 0; rt < 4; ++rt)
            #pragma unroll
            for (int ct = 0; ct < 4; ++ct)
                #pragma unroll
                for (int j = 0; j < 4; ++j) {
                    int row = rt * 16 + (lane >> 4) * 4 + j;
                    int col = ct * 16 + (lane & 15);
                    int n = n0 + n_off + col;
                    float v = acc[rt][ct][j];
                    if (n >= og_start) v = 1.0f / (1.0f + expf(-v));
                    Cw[row * 72 + col] = f2bf(v);
                }
        // same-wave LDS write->read: compiler orders via lgkmcnt; no barrier needed
        #pragma unroll
        for (int it = 0; it < 8; ++it) {
            int row = it * 8 + (lane >> 3);
            int c8 = (lane & 7) * 8;
            uint4 val = *reinterpret_cast<const uint4*>(&Cw[row * 72 + c8]);
            *reinterpret_cast<uint4*>((u16*)Cout + (size_t)(m0 + m_off + row) * ldc + n0 + n_off + c8) = val;
        }
    } else {
        #pragma unroll
        for (int rt = 0; rt < 4; ++rt)
            #pragma unroll
            for (int ct = 0; ct < 4; ++ct)
                #pragma unroll
                for (int j = 0; j < 4; ++j) {
                    int m = m0 + m_off + rt * 16 + (lane >> 4) * 4 + j;
                    int n = n0 + n_off + ct * 16 + (lane & 15);
                    ((float*)Cout)[(size_t)m * ldc + n] = acc[rt][ct][j];
                }
    }
}

// ---------- R1: per-chunk U^T = (v .* w)^T-layout MFMA ----------
// U stored [bh][chunk][c(256)][r(128)] bf16 (i.e. U^T); Gc = chunk total decay.
__global__ __launch_bounds__(256) void r1_kernel(const u16* __restrict__ proj,
                                                 const float* __restrict__ l2a,
                                                 u16* __restrict__ U,
                                                 float* __restrict__ Gc) {
    __shared__ u16 kT[128 * 72];   // kT[r][s]
    __shared__ u16 vT[256 * 72];   // vT[c][s], scaled by w_s
    __shared__ float Wsh[64];
    int bid = blockIdx.x;
    int c = bid & 63, bh = bid >> 6;
    int b = bh >> 3, h = bh & 7;
    int c0 = c * CHUNK;
    int tid = threadIdx.x, lane = tid & 63, wave = tid >> 6;
    size_t rowbase = (size_t)b * SEQ + c0;
    if (wave == 0) {
        float L = l2a[(rowbase + lane) * NH + h];
        #pragma unroll
        for (int d = 1; d < 64; d <<= 1) {
            float u = __shfl_up(L, d, 64);
            if (lane >= d) L += u;
        }
        float Lend = __shfl(L, 63, 64);
        Wsh[lane] = exp2f(Lend - L);
        if (lane == 0) Gc[bh * NCHUNK + c] = exp2f(Lend);
    }
    __syncthreads();
    // stage kT (transpose in LDS)
    #pragma unroll
    for (int j = 0; j < 4; ++j) {
        int cid = tid + j * 256;
        int s = cid >> 4, r = (cid & 15) * 8;
        uint4 v = *(const uint4*)(proj + (rowbase + s) * NPROJ + 1024 + h * DKH + r);
        u16 e[8]; *(uint4*)e = v;
        #pragma unroll
        for (int i = 0; i < 8; ++i) kT[(r + i) * 72 + s] = e[i];
    }
    // stage vT scaled by w_s
    #pragma unroll
    for (int j = 0; j < 8; ++j) {
        int cid = tid + j * 256;
        int s = cid >> 5, cc = (cid & 31) * 8;
        float w = Wsh[s];
        uint4 v = *(const uint4*)(proj + (rowbase + s) * NPROJ + 2048 + h * DVH + cc);
        u16 e[8]; *(uint4*)e = v;
        #pragma unroll
        for (int i = 0; i < 8; ++i) vT[(cc + i) * 72 + s] = f2bf(bf2f(e[i]) * w);
    }
    __syncthreads();
    // U^T[c][r] = sum_s (w_s v[s][c]) k[s][r]; wave owns c-rows [64*wave, +64)
    short8 afr[4][2];
    #pragma unroll
    for (int rt = 0; rt < 4; ++rt)
        #pragma unroll
        for (int kk = 0; kk < 2; ++kk)
            afr[rt][kk] = *reinterpret_cast<const short8*>(
                &vT[(wave * 64 + rt * 16 + (lane & 15)) * 72 + kk * 32 + (lane >> 4) * 8]);
    size_t ubase = (size_t)(bh * NCHUNK + c) * (DVH * DKH);
    #pragma unroll
    for (int ct = 0; ct < 8; ++ct) {
        f32x4 acc[4] = {};
        #pragma unroll
        for (int kk = 0; kk < 2; ++kk) {
            short8 bfr = *reinterpret_cast<const short8*>(
                &kT[(ct * 16 + (lane & 15)) * 72 + kk * 32 + (lane >> 4) * 8]);
            #pragma unroll
            for (int rt = 0; rt < 4; ++rt)
                acc[rt] = __builtin_amdgcn_mfma_f32_16x16x32_bf16(afr[rt][kk], bfr, acc[rt], 0, 0, 0);
        }
        #pragma unroll
        for (int rt = 0; rt < 4; ++rt)
            #pragma unroll
            for (int j = 0; j < 4; ++j) {
                int ccr = wave * 64 + rt * 16 + (lane >> 4) * 4 + j;
                int rr = ct * 16 + (lane & 15);
                U[ubase + (size_t)ccr * DKH + rr] = f2bf(acc[rt][j]);
            }
    }
}

// ---------- R2: sequential scan over chunks (in-place U -> S_prefix) ----------
__global__ __launch_bounds__(256) void r2_kernel(u16* __restrict__ U, const float* __restrict__ Gc) {
    int bh = blockIdx.x >> 5;
    int e0 = ((blockIdx.x & 31) * 256 + threadIdx.x) * 4;
    const float* g = Gc + bh * NCHUNK;
    size_t base = (size_t)bh * NCHUNK * (DVH * DKH) + e0;
    float s0 = 0.f, s1 = 0.f, s2 = 0.f, s3 = 0.f;
    for (int c = 0; c < NCHUNK; ++c) {
        u16* p = U + base + (size_t)c * (DVH * DKH);
        uint2 u = *(const uint2*)p;
        u16 e[4]; *(uint2*)e = u;
        u16 o[4] = { f2bf(s0), f2bf(s1), f2bf(s2), f2bf(s3) };
        *(uint2*)p = *(const uint2*)o;          // write S_prefix[c]
        float G = g[c];
        s0 = G * s0 + bf2f(e[0]);
        s1 = G * s1 + bf2f(e[1]);
        s2 = G * s2 + bf2f(e[2]);
        s3 = G * s3 + bf2f(e[3]);
    }
}

// ---------- R3: chunk outputs (inter + intra) fused with og multiply ----------
__global__ __launch_bounds__(256) void r3_kernel(const u16* __restrict__ proj,
                                                 const u16* __restrict__ Sp,
                                                 const float* __restrict__ l2a,
                                                 u16* __restrict__ z) {
    __shared__ u16 vT[256 * 72];   // vT[c][s]
    __shared__ u16 P[64 * 72];     // P[t][s] decayed, bf16
    __shared__ float Lsh[64];
    int bid = blockIdx.x;
    int c = bid & 63, bh = bid >> 6;
    int b = bh >> 3, h = bh & 7;
    int c0 = c * CHUNK;
    int tid = threadIdx.x, lane = tid & 63, wave = tid >> 6;
    size_t rowbase = (size_t)b * SEQ + c0;
    if (wave == 0) {
        float L = l2a[(rowbase + lane) * NH + h];
        #pragma unroll
        for (int d = 1; d < 64; d <<= 1) {
            float u = __shfl_up(L, d, 64);
            if (lane >= d) L += u;
        }
        Lsh[lane] = L;
    }
    // stage vT (unscaled)
    #pragma unroll
    for (int j = 0; j < 8; ++j) {
        int cid = tid + j * 256;
        int s = cid >> 5, cc = (cid & 31) * 8;
        uint4 v = *(const uint4*)(proj + (rowbase + s) * NPROJ + 2048 + h * DVH + cc);
        u16 e[8]; *(uint4*)e = v;
        #pragma unroll
        for (int i = 0; i < 8; ++i) vT[(cc + i) * 72 + s] = e[i];
    }
    __syncthreads();
    // phase 1a: P strip rows [16*wave, +16): P[t][s] = (q k^T)[t][s] * exp2(L_t - L_s), causal
    {
        f32x4 pacc[4] = {};
        #pragma unroll
        for (int kk = 0; kk < 4; ++kk) {
            short8 a = *reinterpret_cast<const short8*>(
                proj + (rowbase + wave * 16 + (lane & 15)) * NPROJ + h * DKH + kk * 32 + (lane >> 4) * 8);
            #pragma unroll
            for (int st = 0; st < 4; ++st) {
                short8 bb = *reinterpret_cast<const short8*>(
                    proj + (rowbase + st * 16 + (lane & 15)) * NPROJ + 1024 + h * DKH + kk * 32 + (lane >> 4) * 8);
                pacc[st] = __builtin_amdgcn_mfma_f32_16x16x32_bf16(a, bb, pacc[st], 0, 0, 0);
            }
        }
        #pragma unroll
        for (int st = 0; st < 4; ++st)
            #pragma unroll
            for (int j = 0; j < 4; ++j) {
                int t = wave * 16 + (lane >> 4) * 4 + j;
                int s = st * 16 + (lane & 15);
                float val = pacc[st][j];
                val = (s <= t) ? val * exp2f(Lsh[t] - Lsh[s]) : 0.f;
                P[t * 72 + s] = f2bf(val);
            }
    }
    // phase 1b: inter = q @ S_prefix (wave owns output cols [64*wave, +64))
    f32x4 acc[4][4] = {};
    size_t spbase = (size_t)(bh * NCHUNK + c) * (DVH * DKH);
    #pragma unroll
    for (int kk = 0; kk < 4; ++kk) {
        short8 a[4];
        #pragma unroll
        for (int rt = 0; rt < 4; ++rt)
            a[rt] = *reinterpret_cast<const short8*>(
                proj + (rowbase + rt * 16 + (lane & 15)) * NPROJ + h * DKH + kk * 32 + (lane >> 4) * 8);
        #pragma unroll
        for (int ct = 0; ct < 4; ++ct) {
            short8 bb = *reinterpret_cast<const short8*>(
                Sp + spbase + (size_t)(wave * 64 + ct * 16 + (lane & 15)) * DKH + kk * 32 + (lane >> 4) * 8);
            #pragma unroll
            for (int rt = 0; rt < 4; ++rt)
                acc[rt][ct] = __builtin_amdgcn_mfma_f32_16x16x32_bf16(a[rt], bb, acc[rt][ct], 0, 0, 0);
        }
    }
    // scale inter by A_t = exp2(L_t)
    #pragma unroll
    for (int rt = 0; rt < 4; ++rt)
        #pragma unroll
        for (int j = 0; j < 4; ++j) {
            float at = exp2f(Lsh[rt * 16 + (lane >> 4) * 4 + j]);
            #pragma unroll
            for (int ct = 0; ct < 4; ++ct) acc[rt][ct][j] *= at;
        }
    __syncthreads();
    // phase 2: intra = P @ v
    #pragma unroll
    for (int kk = 0; kk < 2; ++kk) {
        short8 pa[4];
        #pragma unroll
        for (int rt = 0; rt < 4; ++rt)
            pa[rt] = *reinterpret_cast<const short8*>(&P[(rt * 16 + (lane & 15)) * 72 + kk * 32 + (lane >> 4) * 8]);
        #pragma unroll
        for (int ct = 0; ct < 4; ++ct) {
            short8 vb = *reinterpret_cast<const short8*>(
                &vT[(wave * 64 + ct * 16 + (lane & 15)) * 72 + kk * 32 + (lane >> 4) * 8]);
            #pragma unroll
            for (int rt = 0; rt < 4; ++rt)
                acc[rt][ct] = __builtin_amdgcn_mfma_f32_16x16x32_bf16(pa[rt], vb, acc[rt][ct], 0, 0, 0);
        }
    }
    // phase 3: z = o * og
    #pragma unroll
    for (int rt = 0; rt < 4; ++rt)
        #pragma unroll
        for (int ct = 0; ct < 4; ++ct)
            #pragma unroll
            for (int j = 0; j < 4; ++j) {
                int t = rt * 16 + (lane >> 4) * 4 + j;
                int cc = wave * 64 + ct * 16 + (lane & 15);
                float og = bf2f(proj[(rowbase + t) * NPROJ + 4096 + h * DVH + cc]);
                float v = acc[rt][ct][j] * og;
                z[(rowbase + t) * (NH * DVH) + h * DVH + cc] = f2bf(v);
            }
}

extern "C" void kernel_launch(void* const* d_in, const int* in_sizes, int n_in,
                              void* d_out, int out_size, void* d_ws, size_t ws_size,
                              hipStream_t stream) {
    const float* x   = (const float*)d_in[0];
    const float* Wq  = (const float*)d_in[1];
    const float* Wk  = (const float*)d_in[2];
    const float* Wv  = (const float*)d_in[3];
    const float* Wo  = (const float*)d_in[4];
    const float* Wg  = (const float*)d_in[5];
    const float* bg  = (const float*)d_in[6];
    const float* Wog = (const float*)d_in[7];
    float* out = (float*)d_out;
    char* ws = (char*)d_ws;

    u16*   xb   = (u16*)(ws + OFF_XB);
    u16*   wcat = (u16*)(ws + OFF_WCAT);
    u16*   wot  = (u16*)(ws + OFF_WOT);
    u16*   proj = (u16*)(ws + OFF_PROJ);
    float* l2a  = (float*)(ws + OFF_L2A);
    float* gc   = (float*)(ws + OFF_GC);
    u16*   U    = (u16*)(ws + OFF_U);
    u16*   z    = (u16*)(ws + OFF_Z);

    cvt_x_kernel<<<8192, 256, 0, stream>>>(x, xb);
    dim3 tb(32, 8);
    transpose_w<<<dim3(32, 32), tb, 0, stream>>>(Wq,  1024, 1024, wcat,               1.0f);
    transpose_w<<<dim3(32, 32), tb, 0, stream>>>(Wk,  1024, 1024, wcat + 1024 * 1024, 0.08838834764831845f); // fold DK^-0.5
    transpose_w<<<dim3(64, 32), tb, 0, stream>>>(Wv,  2048, 1024, wcat + 2048 * 1024, 1.0f);
    transpose_w<<<dim3(64, 32), tb, 0, stream>>>(Wog, 2048, 1024, wcat + 4096 * 1024, 1.0f);
    transpose_w<<<dim3(32, 64), tb, 0, stream>>>(Wo,  1024, 2048, wot,                1.0f);
    alpha_kernel<<<8192, 256, 0, stream>>>(x, Wg, bg, l2a);
    // projections: [8192,1024] @ [6144,1024]^T -> proj bf16 (sigmoid on og cols)
    gemm_glds<1><<<dim3(48, 64), 256, 0, stream>>>(xb, 1024, wcat, 1024, proj, NPROJ, 1024, 4096);
    r1_kernel<<<BATCH * NH * NCHUNK, 256, 0, stream>>>(proj, l2a, U, gc);
    r2_kernel<<<512, 256, 0, stream>>>(U, gc);
    r3_kernel<<<BATCH * NH * NCHUNK, 256, 0, stream>>>(proj, U, l2a, z);
    // final: [8192,2048] @ [1024,2048]^T -> d_out f32
    gemm_glds<0><<<dim3(8, 64), 256, 0, stream>>>(z, 2048, wot, 2048, out, 1024, 2048, 1 << 30);
}

// Round 6
// 586.476 us; speedup vs baseline: 1.6996x; 1.0366x over previous
//
#include <hip/hip_runtime.h>
#include <cstdint>
#include <cstddef>

typedef unsigned short u16;
typedef unsigned int   u32;
typedef __attribute__((ext_vector_type(8))) short short8;   // 8 bf16 (4 VGPRs) MFMA A/B frag
typedef __attribute__((ext_vector_type(4))) float f32x4;    // MFMA C/D frag

// ---------- bf16 helpers (round-to-nearest-even) ----------
__device__ __forceinline__ u16 f2bf(float f) {
    union { float f; u32 u; } v; v.f = f;
    u32 r = v.u + 0x7fffu + ((v.u >> 16) & 1u);
    return (u16)(r >> 16);
}
__device__ __forceinline__ float bf2f(u16 b) {
    union { u32 u; float f; } v; v.u = ((u32)b) << 16;
    return v.f;
}

// async global->LDS, 16B per lane. HW: lds dest = wave-uniform base + lane*16.
__device__ __forceinline__ void gload16(const u16* g, u16* l) {
    __builtin_amdgcn_global_load_lds(
        (const __attribute__((address_space(1))) u32*)g,
        (__attribute__((address_space(3))) u32*)l,
        16, 0, 0);
}

// ---------- constants ----------
#define SEQ   4096
#define BATCH 2
#define NH    8
#define DKH   128
#define DVH   256
#define DMODEL 1024
#define NPROJ 6144          // q(1024) | k(1024) | v(2048) | og(2048)
#define CHUNK 64
#define NCHUNK (SEQ / CHUNK)  // 64

// ws layout (byte offsets)
#define OFF_XB    0u                 // x bf16              [8192][1024]    16,777,216
#define OFF_WCAT  16777216u          // WcatT bf16          [6144][1024]    12,582,912
#define OFF_WOT   29360128u          // WoT bf16            [1024][2048]     4,194,304
#define OFF_PROJ  33554432u          // proj bf16           [8192][6144]   100,663,296
#define OFF_L2A   134217728u         // log2(alpha) f32     [8192][8]          262,144
#define OFF_GC    134479872u         // per-chunk decay f32 [16][64]             4,096
#define OFF_U     134483968u         // U / S_prefix bf16   [16][64][256][128] 67,108,864
#define OFF_Z     201592832u         // z = o*og bf16       [8192][2048]    33,554,432
// total 235,147,264 bytes

// ---------- f32 -> bf16 convert (x) ----------
__global__ __launch_bounds__(256) void cvt_x_kernel(const float* __restrict__ x,
                                                    u16* __restrict__ xb) {
    int i = (blockIdx.x * 256 + threadIdx.x) * 4;
    float4 v = *(const float4*)(x + i);
    u16 o[4] = { f2bf(v.x), f2bf(v.y), f2bf(v.z), f2bf(v.w) };
    *(uint2*)(xb + i) = *(const uint2*)o;
}

// ---------- weight transpose + bf16 (out[n][k] = W[k][n] * scale) ----------
__global__ __launch_bounds__(256) void transpose_w(const float* __restrict__ W, int N, int K,
                                                   u16* __restrict__ outp, float scale) {
    __shared__ float t[32][33];
    int n0 = blockIdx.x * 32, k0 = blockIdx.y * 32;
    int tx = threadIdx.x, ty = threadIdx.y;
    #pragma unroll
    for (int j = 0; j < 4; ++j)
        t[ty + j * 8][tx] = W[(size_t)(k0 + ty + j * 8) * N + n0 + tx];
    __syncthreads();
    #pragma unroll
    for (int j = 0; j < 4; ++j)
        outp[(size_t)(n0 + ty + j * 8) * K + k0 + tx] = f2bf(t[tx][ty + j * 8] * scale);
}

// ---------- gate kernel: l2a = log2(sigmoid((x@Wg + bg)/16)), pure f32 ----------
__global__ __launch_bounds__(256) void alpha_kernel(const float* __restrict__ x,
                                                    const float* __restrict__ Wg,
                                                    const float* __restrict__ bg,
                                                    float* __restrict__ l2a) {
    __shared__ float xr[DMODEL];
    int row = blockIdx.x;
    for (int i = threadIdx.x; i < DMODEL; i += 256) xr[i] = x[(size_t)row * DMODEL + i];
    __syncthreads();
    int wave = threadIdx.x >> 6, lane = threadIdx.x & 63;
    #pragma unroll
    for (int hh = 0; hh < 2; ++hh) {
        int h = wave * 2 + hh;
        float p = 0.f;
        for (int i = lane; i < DMODEL; i += 64) p += xr[i] * Wg[i * NH + h];
        #pragma unroll
        for (int d = 32; d; d >>= 1) p += __shfl_down(p, d, 64);
        if (lane == 0) {
            float zz = (p + bg[h]) * (1.0f / 16.0f);
            float a = 1.0f / (1.0f + expf(-zz));
            l2a[row * NH + h] = log2f(a);
        }
    }
}

// ---------- 256x256 deep-pipelined bf16 GEMM: C[M,N] = A[M,K] @ B[N,K]^T ----------
// 512 thr / 8 waves (2Mx4N), BK=32, 4-deep circular LDS buffer (128 KiB),
// stage 2 K-tiles ahead via global_load_lds; boundary s_waitcnt vmcnt(4)+s_barrier
// (never drains to 0 in steady state). T2 swizzle: quad ^= (row>>2)&3, applied as
// inverse-swizzled GLOBAL source (linear LDS dest, rule #21) + swizzled ds_read.
// (row&3 variant is a bank no-op since lane&3==row&3 in the read pattern;
//  (row>>2)&3 splits each 4-bank group from 8 lanes to 2 -> free per m136.)
// EPI=1: bf16 out via LDS-bounce, sigmoid for n >= og_start. EPI=0: f32 out.
template <int EPI>
__global__ __launch_bounds__(512, 2) void gemm256(const u16* __restrict__ A, int lda,
                                                  const u16* __restrict__ B, int ldb,
                                                  void* __restrict__ Cout, int ldc,
                                                  int K, int nTN, int og_start) {
    __shared__ u16 lds[65536];          // 128 KiB: A bufs [4][256][32] | B bufs [4][256][32]
    const int tid = threadIdx.x;
    const int lane = tid & 63, wid = tid >> 6;
    const int wr = wid >> 2, wc = wid & 3;
    // XCD-bijective swizzle (gridDim.x % 8 == 0)
    const int cpx = gridDim.x >> 3;
    const int wg = (blockIdx.x & 7) * cpx + (blockIdx.x >> 3);
    const int m0 = (wg / nTN) * 256, n0 = (wg % nTN) * 256;

    // staging: thread covers physical (row rsub = tid>>2, quad tid&3) of a 128-row half;
    // global source pre-swizzled: physical quad p holds global quad p^((row>>2)&3)
    const int rsub = tid >> 2;
    const int ql = (tid & 3) ^ ((tid >> 4) & 3);     // (rsub>>2)&3 == (tid>>4)&3
    const size_t ag0 = (size_t)(m0 + rsub) * lda + ql * 8;
    const size_t ag1 = (size_t)(m0 + 128 + rsub) * lda + ql * 8;
    const size_t bg0 = (size_t)(n0 + rsub) * ldb + ql * 8;
    const size_t bg1 = (size_t)(n0 + 128 + rsub) * ldb + ql * 8;
    const int sdw = wid * 512;          // wave-uniform LDS chunk within a half

#define STG_A(t_, h_) gload16(A + ((h_) ? ag1 : ag0) + (size_t)(t_) * 32, \
                              lds + ((t_) & 3) * 8192 + (h_) * 4096 + sdw)
#define STG_B(t_, h_) gload16(B + ((h_) ? bg1 : bg0) + (size_t)(t_) * 32, \
                              lds + 32768 + ((t_) & 3) * 8192 + (h_) * 4096 + sdw)

    // fragment read: row = base16 + (lane&15)  ->  (row>>2)&3 == (lane>>2)&3
    const int qr = ((lane >> 4) ^ ((lane >> 2) & 3)) * 8;
    const int arow = (wr * 128 + (lane & 15)) * 32 + qr;
    const int brow = 32768 + (wc * 64 + (lane & 15)) * 32 + qr;

    // prologue: stage tiles 0,1; retire tile 0 (vmcnt(4)), keep tile 1 in flight
    STG_A(0, 0); STG_A(0, 1); STG_B(0, 0); STG_B(0, 1);
    STG_A(1, 0); STG_A(1, 1); STG_B(1, 0); STG_B(1, 1);
    asm volatile("s_waitcnt vmcnt(4)\n\ts_barrier" ::: "memory");

    f32x4 acc[8][4] = {};
    const int NT = K >> 5;
    for (int t = 0; t < NT; ++t) {
        const u16* buf = lds + (t & 3) * 8192;
        const bool pre = (t + 2) < NT;
        // phase A: stage A(t+2) || ds_read b[4], a[0..3] || 16 MFMA
        if (pre) { STG_A(t + 2, 0); STG_A(t + 2, 1); }
        short8 bfr[4], afr[4];
        #pragma unroll
        for (int ct = 0; ct < 4; ++ct) bfr[ct] = *(const short8*)(buf + brow + ct * 512);
        #pragma unroll
        for (int rt = 0; rt < 4; ++rt) afr[rt] = *(const short8*)(buf + arow + rt * 512);
        __builtin_amdgcn_s_setprio(1);
        #pragma unroll
        for (int rt = 0; rt < 4; ++rt)
            #pragma unroll
            for (int ct = 0; ct < 4; ++ct)
                acc[rt][ct] = __builtin_amdgcn_mfma_f32_16x16x32_bf16(afr[rt], bfr[ct], acc[rt][ct], 0, 0, 0);
        __builtin_amdgcn_s_setprio(0);
        // phase B: stage B(t+2) || ds_read a[4..7] || 16 MFMA
        if (pre) { STG_B(t + 2, 0); STG_B(t + 2, 1); }
        #pragma unroll
        for (int rt = 0; rt < 4; ++rt) afr[rt] = *(const short8*)(buf + arow + (rt + 4) * 512);
        __builtin_amdgcn_s_setprio(1);
        #pragma unroll
        for (int rt = 0; rt < 4; ++rt)
            #pragma unroll
            for (int ct = 0; ct < 4; ++ct)
                acc[rt + 4][ct] = __builtin_amdgcn_mfma_f32_16x16x32_bf16(afr[rt], bfr[ct], acc[rt + 4][ct], 0, 0, 0);
        __builtin_amdgcn_s_setprio(0);
        // boundary: publish tile t+1; tile t+2's 4 loads stay in flight
        if (t < NT - 2)       asm volatile("s_waitcnt vmcnt(4)\n\ts_barrier" ::: "memory");
        else if (t == NT - 2) asm volatile("s_waitcnt vmcnt(0)\n\ts_barrier" ::: "memory");
    }
#undef STG_A
#undef STG_B

    __syncthreads();   // safe drain before LDS reuse by epilogue
    if (EPI) {
        // LDS-bounce: per wave [64][72] region, two 64-row passes -> coalesced uint4 stores
        u16* Cw = lds + wid * 4608;
        #pragma unroll
        for (int pass = 0; pass < 2; ++pass) {
            #pragma unroll
            for (int rt = 0; rt < 4; ++rt)
                #pragma unroll
                for (int ct = 0; ct < 4; ++ct)
                    #pragma unroll
                    for (int j = 0; j < 4; ++j) {
                        int row = rt * 16 + (lane >> 4) * 4 + j;
                        int col = ct * 16 + (lane & 15);
                        float v = acc[pass * 4 + rt][ct][j];
                        if (n0 + wc * 64 + col >= og_start) v = 1.0f / (1.0f + expf(-v));
                        Cw[row * 72 + col] = f2bf(v);
                    }
            #pragma unroll
            for (int it = 0; it < 8; ++it) {
                int row = it * 8 + (lane >> 3);
                int c8 = (lane & 7) * 8;
                uint4 val = *reinterpret_cast<const uint4*>(&Cw[row * 72 + c8]);
                *reinterpret_cast<uint4*>((u16*)Cout +
                    (size_t)(m0 + wr * 128 + pass * 64 + row) * ldc + n0 + wc * 64 + c8) = val;
            }
        }
    } else {
        #pragma unroll
        for (int rt = 0; rt < 8; ++rt)
            #pragma unroll
            for (int ct = 0; ct < 4; ++ct)
                #pragma unroll
                for (int j = 0; j < 4; ++j) {
                    int m = m0 + wr * 128 + rt * 16 + (lane >> 4) * 4 + j;
                    int n = n0 + wc * 64 + ct * 16 + (lane & 15);
                    ((float*)Cout)[(size_t)m * ldc + n] = acc[rt][ct][j];
                }
    }
}

// ---------- 128x128 bf16 MFMA GEMM, m97-style (kept for the final f32 GEMM) ----------
template <int EPI>
__global__ __launch_bounds__(256) void gemm_glds(const u16* __restrict__ A, int lda,
                                                 const u16* __restrict__ B, int ldb,
                                                 void* __restrict__ Cout, int ldc,
                                                 int K, int og_start) {
    __shared__ u16 smem[18432];
    u16* As = smem;
    u16* Bs = smem + 4096;
    const int tid = threadIdx.x;
    const int lane = tid & 63, wave = tid >> 6;
    const int m0 = blockIdx.y * 128, n0 = blockIdx.x * 128;
    const int m_off = (wave & 1) * 64, n_off = (wave >> 1) * 64;
    const int r = tid >> 2, kg = (tid & 3) * 8;
    f32x4 acc[4][4] = {};
    for (int k0 = 0; k0 < K; k0 += 32) {
        #pragma unroll
        for (int i = 0; i < 2; ++i) {
            int row = i * 64 + r;
            gload16(A + (size_t)(m0 + row) * lda + k0 + kg, As + (i * 256 + (tid & 192)) * 8);
            gload16(B + (size_t)(n0 + row) * ldb + k0 + kg, Bs + (i * 256 + (tid & 192)) * 8);
        }
        __syncthreads();
        short8 a[4], b[4];
        #pragma unroll
        for (int rt = 0; rt < 4; ++rt)
            a[rt] = *reinterpret_cast<const short8*>(&As[(m_off + rt * 16 + (lane & 15)) * 32 + (lane >> 4) * 8]);
        #pragma unroll
        for (int ct = 0; ct < 4; ++ct)
            b[ct] = *reinterpret_cast<const short8*>(&Bs[(n_off + ct * 16 + (lane & 15)) * 32 + (lane >> 4) * 8]);
        #pragma unroll
        for (int rt = 0; rt < 4; ++rt)
            #pragma unroll
            for (int ct = 0; ct < 4; ++ct)
                acc[rt][ct] = __builtin_amdgcn_mfma_f32_16x16x32_bf16(a[rt], b[ct], acc[rt][ct], 0, 0, 0);
        __syncthreads();
    }
    if (EPI) {
        u16* Cw = smem + wave * 4608;
        #pragma unroll
        for (int rt = 0; rt < 4; ++rt)
            #pragma unroll
            for (int ct = 0; ct < 4; ++ct)
                #pragma unroll
                for (int j = 0; j < 4; ++j) {
                    int row = rt * 16 + (lane >> 4) * 4 + j;
                    int col = ct * 16 + (lane & 15);
                    int n = n0 + n_off + col;
                    float v = acc[rt][ct][j];
                    if (n >= og_start) v = 1.0f / (1.0f + expf(-v));
                    Cw[row * 72 + col] = f2bf(v);
                }
        #pragma unroll
        for (int it = 0; it < 8; ++it) {
            int row = it * 8 + (lane >> 3);
            int c8 = (lane & 7) * 8;
            uint4 val = *reinterpret_cast<const uint4*>(&Cw[row * 72 + c8]);
            *reinterpret_cast<uint4*>((u16*)Cout + (size_t)(m0 + m_off + row) * ldc + n0 + n_off + c8) = val;
        }
    } else {
        #pragma unroll
        for (int rt = 0; rt < 4; ++rt)
            #pragma unroll
            for (int ct = 0; ct < 4; ++ct)
                #pragma unroll
                for (int j = 0; j < 4; ++j) {
                    int m = m0 + m_off + rt * 16 + (lane >> 4) * 4 + j;
                    int n = n0 + n_off + ct * 16 + (lane & 15);
                    ((float*)Cout)[(size_t)m * ldc + n] = acc[rt][ct][j];
                }
    }
}

// ---------- R1: per-chunk U^T = (v .* w)^T-layout MFMA ----------
__global__ __launch_bounds__(256) void r1_kernel(const u16* __restrict__ proj,
                                                 const float* __restrict__ l2a,
                                                 u16* __restrict__ U,
                                                 float* __restrict__ Gc) {
    __shared__ u16 kT[128 * 72];   // kT[r][s]
    __shared__ u16 vT[256 * 72];   // vT[c][s], scaled by w_s
    __shared__ float Wsh[64];
    int bid = blockIdx.x;
    int c = bid & 63, bh = bid >> 6;
    int b = bh >> 3, h = bh & 7;
    int c0 = c * CHUNK;
    int tid = threadIdx.x, lane = tid & 63, wave = tid >> 6;
    size_t rowbase = (size_t)b * SEQ + c0;
    if (wave == 0) {
        float L = l2a[(rowbase + lane) * NH + h];
        #pragma unroll
        for (int d = 1; d < 64; d <<= 1) {
            float u = __shfl_up(L, d, 64);
            if (lane >= d) L += u;
        }
        float Lend = __shfl(L, 63, 64);
        Wsh[lane] = exp2f(Lend - L);
        if (lane == 0) Gc[bh * NCHUNK + c] = exp2f(Lend);
    }
    __syncthreads();
    #pragma unroll
    for (int j = 0; j < 4; ++j) {
        int cid = tid + j * 256;
        int s = cid >> 4, r = (cid & 15) * 8;
        uint4 v = *(const uint4*)(proj + (rowbase + s) * NPROJ + 1024 + h * DKH + r);
        u16 e[8]; *(uint4*)e = v;
        #pragma unroll
        for (int i = 0; i < 8; ++i) kT[(r + i) * 72 + s] = e[i];
    }
    #pragma unroll
    for (int j = 0; j < 8; ++j) {
        int cid = tid + j * 256;
        int s = cid >> 5, cc = (cid & 31) * 8;
        float w = Wsh[s];
        uint4 v = *(const uint4*)(proj + (rowbase + s) * NPROJ + 2048 + h * DVH + cc);
        u16 e[8]; *(uint4*)e = v;
        #pragma unroll
        for (int i = 0; i < 8; ++i) vT[(cc + i) * 72 + s] = f2bf(bf2f(e[i]) * w);
    }
    __syncthreads();
    short8 afr[4][2];
    #pragma unroll
    for (int rt = 0; rt < 4; ++rt)
        #pragma unroll
        for (int kk = 0; kk < 2; ++kk)
            afr[rt][kk] = *reinterpret_cast<const short8*>(
                &vT[(wave * 64 + rt * 16 + (lane & 15)) * 72 + kk * 32 + (lane >> 4) * 8]);
    size_t ubase = (size_t)(bh * NCHUNK + c) * (DVH * DKH);
    #pragma unroll
    for (int ct = 0; ct < 8; ++ct) {
        f32x4 acc[4] = {};
        #pragma unroll
        for (int kk = 0; kk < 2; ++kk) {
            short8 bfr = *reinterpret_cast<const short8*>(
                &kT[(ct * 16 + (lane & 15)) * 72 + kk * 32 + (lane >> 4) * 8]);
            #pragma unroll
            for (int rt = 0; rt < 4; ++rt)
                acc[rt] = __builtin_amdgcn_mfma_f32_16x16x32_bf16(afr[rt][kk], bfr, acc[rt], 0, 0, 0);
        }
        #pragma unroll
        for (int rt = 0; rt < 4; ++rt)
            #pragma unroll
            for (int j = 0; j < 4; ++j) {
                int ccr = wave * 64 + rt * 16 + (lane >> 4) * 4 + j;
                int rr = ct * 16 + (lane & 15);
                U[ubase + (size_t)ccr * DKH + rr] = f2bf(acc[rt][j]);
            }
    }
}

// ---------- R2: sequential scan over chunks (in-place U -> S_prefix) ----------
__global__ __launch_bounds__(256) void r2_kernel(u16* __restrict__ U, const float* __restrict__ Gc) {
    int bh = blockIdx.x >> 5;
    int e0 = ((blockIdx.x & 31) * 256 + threadIdx.x) * 4;
    const float* g = Gc + bh * NCHUNK;
    size_t base = (size_t)bh * NCHUNK * (DVH * DKH) + e0;
    float s0 = 0.f, s1 = 0.f, s2 = 0.f, s3 = 0.f;
    for (int c = 0; c < NCHUNK; ++c) {
        u16* p = U + base + (size_t)c * (DVH * DKH);
        uint2 u = *(const uint2*)p;
        u16 e[4]; *(uint2*)e = u;
        u16 o[4] = { f2bf(s0), f2bf(s1), f2bf(s2), f2bf(s3) };
        *(uint2*)p = *(const uint2*)o;
        float G = g[c];
        s0 = G * s0 + bf2f(e[0]);
        s1 = G * s1 + bf2f(e[1]);
        s2 = G * s2 + bf2f(e[2]);
        s3 = G * s3 + bf2f(e[3]);
    }
}

// ---------- R3: chunk outputs (inter + intra) fused with og multiply ----------
__global__ __launch_bounds__(256) void r3_kernel(const u16* __restrict__ proj,
                                                 const u16* __restrict__ Sp,
                                                 const float* __restrict__ l2a,
                                                 u16* __restrict__ z) {
    __shared__ u16 vT[256 * 72];   // vT[c][s]
    __shared__ u16 P[64 * 72];     // P[t][s] decayed, bf16
    __shared__ float Lsh[64];
    int bid = blockIdx.x;
    int c = bid & 63, bh = bid >> 6;
    int b = bh >> 3, h = bh & 7;
    int c0 = c * CHUNK;
    int tid = threadIdx.x, lane = tid & 63, wave = tid >> 6;
    size_t rowbase = (size_t)b * SEQ + c0;
    if (wave == 0) {
        float L = l2a[(rowbase + lane) * NH + h];
        #pragma unroll
        for (int d = 1; d < 64; d <<= 1) {
            float u = __shfl_up(L, d, 64);
            if (lane >= d) L += u;
        }
        Lsh[lane] = L;
    }
    #pragma unroll
    for (int j = 0; j < 8; ++j) {
        int cid = tid + j * 256;
        int s = cid >> 5, cc = (cid & 31) * 8;
        uint4 v = *(const uint4*)(proj + (rowbase + s) * NPROJ + 2048 + h * DVH + cc);
        u16 e[8]; *(uint4*)e = v;
        #pragma unroll
        for (int i = 0; i < 8; ++i) vT[(cc + i) * 72 + s] = e[i];
    }
    __syncthreads();
    {
        f32x4 pacc[4] = {};
        #pragma unroll
        for (int kk = 0; kk < 4; ++kk) {
            short8 a = *reinterpret_cast<const short8*>(
                proj + (rowbase + wave * 16 + (lane & 15)) * NPROJ + h * DKH + kk * 32 + (lane >> 4) * 8);
            #pragma unroll
            for (int st = 0; st < 4; ++st) {
                short8 bb = *reinterpret_cast<const short8*>(
                    proj + (rowbase + st * 16 + (lane & 15)) * NPROJ + 1024 + h * DKH + kk * 32 + (lane >> 4) * 8);
                pacc[st] = __builtin_amdgcn_mfma_f32_16x16x32_bf16(a, bb, pacc[st], 0, 0, 0);
            }
        }
        #pragma unroll
        for (int st = 0; st < 4; ++st)
            #pragma unroll
            for (int j = 0; j < 4; ++j) {
                int t = wave * 16 + (lane >> 4) * 4 + j;
                int s = st * 16 + (lane & 15);
                float val = pacc[st][j];
                val = (s <= t) ? val * exp2f(Lsh[t] - Lsh[s]) : 0.f;
                P[t * 72 + s] = f2bf(val);
            }
    }
    f32x4 acc[4][4] = {};
    size_t spbase = (size_t)(bh * NCHUNK + c) * (DVH * DKH);
    #pragma unroll
    for (int kk = 0; kk < 4; ++kk) {
        short8 a[4];
        #pragma unroll
        for (int rt = 0; rt < 4; ++rt)
            a[rt] = *reinterpret_cast<const short8*>(
                proj + (rowbase + rt * 16 + (lane & 15)) * NPROJ + h * DKH + kk * 32 + (lane >> 4) * 8);
        #pragma unroll
        for (int ct = 0; ct < 4; ++ct) {
            short8 bb = *reinterpret_cast<const short8*>(
                Sp + spbase + (size_t)(wave * 64 + ct * 16 + (lane & 15)) * DKH + kk * 32 + (lane >> 4) * 8);
            #pragma unroll
            for (int rt = 0; rt < 4; ++rt)
                acc[rt][ct] = __builtin_amdgcn_mfma_f32_16x16x32_bf16(a[rt], bb, acc[rt][ct], 0, 0, 0);
        }
    }
    #pragma unroll
    for (int rt = 0; rt < 4; ++rt)
        #pragma unroll
        for (int j = 0; j < 4; ++j) {
            float at = exp2f(Lsh[rt * 16 + (lane >> 4) * 4 + j]);
            #pragma unroll
            for (int ct = 0; ct < 4; ++ct) acc[rt][ct][j] *= at;
        }
    __syncthreads();
    #pragma unroll
    for (int kk = 0; kk < 2; ++kk) {
        short8 pa[4];
        #pragma unroll
        for (int rt = 0; rt < 4; ++rt)
            pa[rt] = *reinterpret_cast<const short8*>(&P[(rt * 16 + (lane & 15)) * 72 + kk * 32 + (lane >> 4) * 8]);
        #pragma unroll
        for (int ct = 0; ct < 4; ++ct) {
            short8 vb = *reinterpret_cast<const short8*>(
                &vT[(wave * 64 + ct * 16 + (lane & 15)) * 72 + kk * 32 + (lane >> 4) * 8]);
            #pragma unroll
            for (int rt = 0; rt < 4; ++rt)
                acc[rt][ct] = __builtin_amdgcn_mfma_f32_16x16x32_bf16(pa[rt], vb, acc[rt][ct], 0, 0, 0);
        }
    }
    #pragma unroll
    for (int rt = 0; rt < 4; ++rt)
        #pragma unroll
        for (int ct = 0; ct < 4; ++ct)
            #pragma unroll
            for (int j = 0; j < 4; ++j) {
                int t = rt * 16 + (lane >> 4) * 4 + j;
                int cc = wave * 64 + ct * 16 + (lane & 15);
                float og = bf2f(proj[(rowbase + t) * NPROJ + 4096 + h * DVH + cc]);
                float v = acc[rt][ct][j] * og;
                z[(rowbase + t) * (NH * DVH) + h * DVH + cc] = f2bf(v);
            }
}

extern "C" void kernel_launch(void* const* d_in, const int* in_sizes, int n_in,
                              void* d_out, int out_size, void* d_ws, size_t ws_size,
                              hipStream_t stream) {
    const float* x   = (const float*)d_in[0];
    const float* Wq  = (const float*)d_in[1];
    const float* Wk  = (const float*)d_in[2];
    const float* Wv  = (const float*)d_in[3];
    const float* Wo  = (const float*)d_in[4];
    const float* Wg  = (const float*)d_in[5];
    const float* bg  = (const float*)d_in[6];
    const float* Wog = (const float*)d_in[7];
    float* out = (float*)d_out;
    char* ws = (char*)d_ws;

    u16*   xb   = (u16*)(ws + OFF_XB);
    u16*   wcat = (u16*)(ws + OFF_WCAT);
    u16*   wot  = (u16*)(ws + OFF_WOT);
    u16*   proj = (u16*)(ws + OFF_PROJ);
    float* l2a  = (float*)(ws + OFF_L2A);
    float* gc   = (float*)(ws + OFF_GC);
    u16*   U    = (u16*)(ws + OFF_U);
    u16*   z    = (u16*)(ws + OFF_Z);

    cvt_x_kernel<<<8192, 256, 0, stream>>>(x, xb);
    dim3 tb(32, 8);
    transpose_w<<<dim3(32, 32), tb, 0, stream>>>(Wq,  1024, 1024, wcat,               1.0f);
    transpose_w<<<dim3(32, 32), tb, 0, stream>>>(Wk,  1024, 1024, wcat + 1024 * 1024, 0.08838834764831845f); // fold DK^-0.5
    transpose_w<<<dim3(64, 32), tb, 0, stream>>>(Wv,  2048, 1024, wcat + 2048 * 1024, 1.0f);
    transpose_w<<<dim3(64, 32), tb, 0, stream>>>(Wog, 2048, 1024, wcat + 4096 * 1024, 1.0f);
    transpose_w<<<dim3(32, 64), tb, 0, stream>>>(Wo,  1024, 2048, wot,                1.0f);
    alpha_kernel<<<8192, 256, 0, stream>>>(x, Wg, bg, l2a);
    // projections: [8192,1024] @ [6144,1024]^T -> proj bf16 (sigmoid on og cols)
    // grid 32x24=768 tiles (768 % 8 == 0 -> bijective XCD swizzle)
    gemm256<1><<<768, 512, 0, stream>>>(xb, 1024, wcat, 1024, proj, NPROJ, 1024, 24, 4096);
    r1_kernel<<<BATCH * NH * NCHUNK, 256, 0, stream>>>(proj, l2a, U, gc);
    r2_kernel<<<512, 256, 0, stream>>>(U, gc);
    r3_kernel<<<BATCH * NH * NCHUNK, 256, 0, stream>>>(proj, U, l2a, z);
    // final: [8192,2048] @ [1024,2048]^T -> d_out f32
    gemm_glds<0><<<dim3(8, 64), 256, 0, stream>>>(z, 2048, wot, 2048, out, 1024, 2048, 1 << 30);
}

// Round 7
// 549.322 us; speedup vs baseline: 1.8146x; 1.0676x over previous
//
#include <hip/hip_runtime.h>
#include <cstdint>
#include <cstddef>

typedef unsigned short u16;
typedef unsigned int   u32;
typedef __attribute__((ext_vector_type(8))) short short8;   // 8 bf16 (4 VGPRs) MFMA A/B frag
typedef __attribute__((ext_vector_type(4))) float f32x4;    // MFMA C/D frag

// ---------- bf16 helpers (round-to-nearest-even) ----------
__device__ __forceinline__ u16 f2bf(float f) {
    union { float f; u32 u; } v; v.f = f;
    u32 r = v.u + 0x7fffu + ((v.u >> 16) & 1u);
    return (u16)(r >> 16);
}
__device__ __forceinline__ float bf2f(u16 b) {
    union { u32 u; float f; } v; v.u = ((u32)b) << 16;
    return v.f;
}

// async global->LDS, 16B per lane. HW: lds dest = wave-uniform base + lane*16.
__device__ __forceinline__ void gload16(const u16* g, u16* l) {
    __builtin_amdgcn_global_load_lds(
        (const __attribute__((address_space(1))) u32*)g,
        (__attribute__((address_space(3))) u32*)l,
        16, 0, 0);
}

// ---------- constants ----------
#define SEQ   4096
#define BATCH 2
#define NH    8
#define DKH   128
#define DVH   256
#define DMODEL 1024
#define NPROJ 6144          // q(1024) | k(1024) | v(2048) | og(2048)
#define CHUNK 64
#define NCHUNK (SEQ / CHUNK)  // 64

// ws layout (byte offsets)
#define OFF_XB    0u                 // x bf16              [8192][1024]    16,777,216
#define OFF_WCAT  16777216u          // WcatT bf16          [6144][1024]    12,582,912
#define OFF_WOT   29360128u          // WoT bf16            [1024][2048]     4,194,304
#define OFF_PROJ  33554432u          // proj bf16           [8192][6144]   100,663,296
#define OFF_L2A   134217728u         // log2(alpha) f32     [8192][8]          262,144
#define OFF_GC    134479872u         // per-chunk decay f32 [16][64]             4,096
#define OFF_U     134483968u         // U / S_prefix bf16   [16][64][256][128] 67,108,864
#define OFF_Z     201592832u         // z = o*og bf16       [8192][2048]    33,554,432
// total 235,147,264 bytes

// ---------- f32 -> bf16 convert (x) ----------
__global__ __launch_bounds__(256) void cvt_x_kernel(const float* __restrict__ x,
                                                    u16* __restrict__ xb) {
    int i = (blockIdx.x * 256 + threadIdx.x) * 4;
    float4 v = *(const float4*)(x + i);
    u16 o[4] = { f2bf(v.x), f2bf(v.y), f2bf(v.z), f2bf(v.w) };
    *(uint2*)(xb + i) = *(const uint2*)o;
}

// ---------- weight transpose + bf16 (out[n][k] = W[k][n] * scale) ----------
__global__ __launch_bounds__(256) void transpose_w(const float* __restrict__ W, int N, int K,
                                                   u16* __restrict__ outp, float scale) {
    __shared__ float t[32][33];
    int n0 = blockIdx.x * 32, k0 = blockIdx.y * 32;
    int tx = threadIdx.x, ty = threadIdx.y;
    #pragma unroll
    for (int j = 0; j < 4; ++j)
        t[ty + j * 8][tx] = W[(size_t)(k0 + ty + j * 8) * N + n0 + tx];
    __syncthreads();
    #pragma unroll
    for (int j = 0; j < 4; ++j)
        outp[(size_t)(n0 + ty + j * 8) * K + k0 + tx] = f2bf(t[tx][ty + j * 8] * scale);
}

// ---------- gate kernel: l2a = log2(sigmoid((x@Wg + bg)/16)), pure f32 ----------
__global__ __launch_bounds__(256) void alpha_kernel(const float* __restrict__ x,
                                                    const float* __restrict__ Wg,
                                                    const float* __restrict__ bg,
                                                    float* __restrict__ l2a) {
    __shared__ float xr[DMODEL];
    int row = blockIdx.x;
    for (int i = threadIdx.x; i < DMODEL; i += 256) xr[i] = x[(size_t)row * DMODEL + i];
    __syncthreads();
    int wave = threadIdx.x >> 6, lane = threadIdx.x & 63;
    #pragma unroll
    for (int hh = 0; hh < 2; ++hh) {
        int h = wave * 2 + hh;
        float p = 0.f;
        for (int i = lane; i < DMODEL; i += 64) p += xr[i] * Wg[i * NH + h];
        #pragma unroll
        for (int d = 32; d; d >>= 1) p += __shfl_down(p, d, 64);
        if (lane == 0) {
            float zz = (p + bg[h]) * (1.0f / 16.0f);
            float a = 1.0f / (1.0f + expf(-zz));
            l2a[row * NH + h] = log2f(a);
        }
    }
}

// ---------- 256x256 deep-pipelined bf16 GEMM: C[M,N] = A[M,K] @ B[N,K]^T ----------
// 512 thr / 8 waves (2Mx4N), BK=32, 4-deep circular LDS buffer (128 KiB).
// Staging runs THREE K-tiles ahead (stage t+3 during t); boundary s_waitcnt vmcnt(4)
// retires tile t+2 -> during tile t+1 its A-frags for t+2 can be read with NO drain.
// A-frag SOFTWARE PIPELINE: frags for tile t+1 are ds_read during tile t, so the
// LDS pipe overlaps the MFMA pipe instead of alternating at each barrier.
// T2 swizzle: quad ^= (row>>1)&3 (even lanes of every octet cover all 4 quads ->
// all 8 bank granules distinct per octet). Applied as inverse-swizzled GLOBAL
// source (linear LDS dest, rule #21) + swizzled ds_read.
// EPI=1: bf16 out via LDS-bounce (stride 80 = conflict-free), sigmoid for n>=og_start.
// EPI=0: f32 out direct.
template <int EPI>
__global__ __launch_bounds__(512, 2) void gemm256(const u16* __restrict__ A, int lda,
                                                  const u16* __restrict__ B, int ldb,
                                                  void* __restrict__ Cout, int ldc,
                                                  int K, int nTN, int og_start) {
    __shared__ u16 lds[65536];          // A bufs [4][256][32] | B bufs [4][256][32]
    const int tid = threadIdx.x;
    const int lane = tid & 63, wid = tid >> 6;
    const int wr = wid >> 2, wc = wid & 3;
    // XCD-bijective swizzle (gridDim.x % 8 == 0)
    const int cpx = gridDim.x >> 3;
    const int wg = (blockIdx.x & 7) * cpx + (blockIdx.x >> 3);
    const int m0 = (wg / nTN) * 256, n0 = (wg % nTN) * 256;

    // staging: thread covers physical (row rsub=tid>>2, quad tid&3) of a 128-row half;
    // physical quad p at row r holds global quad p ^ ((r>>1)&3)
    const int rsub = tid >> 2;
    const int ql = (tid & 3) ^ ((tid >> 3) & 3);     // (rsub>>1)&3 == (tid>>3)&3
    const size_t ag0 = (size_t)(m0 + rsub) * lda + ql * 8;
    const size_t ag1 = (size_t)(m0 + 128 + rsub) * lda + ql * 8;
    const size_t bg0 = (size_t)(n0 + rsub) * ldb + ql * 8;
    const size_t bg1 = (size_t)(n0 + 128 + rsub) * ldb + ql * 8;
    const int sdw = wid * 512;          // wave-uniform LDS chunk within a half

#define STG_A(t_, h_) gload16(A + ((h_) ? ag1 : ag0) + (size_t)(t_) * 32, \
                              lds + ((t_) & 3) * 8192 + (h_) * 4096 + sdw)
#define STG_B(t_, h_) gload16(B + ((h_) ? bg1 : bg0) + (size_t)(t_) * 32, \
                              lds + 32768 + ((t_) & 3) * 8192 + (h_) * 4096 + sdw)

    // frag read: row = base16 + (lane&15) -> (row>>1)&3 == (lane>>1)&3 (base16 % 16 == 0)
    const int qr = ((lane >> 4) ^ ((lane >> 1) & 3)) * 8;
    const int arow = (wr * 128 + (lane & 15)) * 32 + qr;
    const int brow = 32768 + (wc * 64 + (lane & 15)) * 32 + qr;

    const int NT = K >> 5;
    // prologue: stage tiles 0,1,2; retire 0,1 (vmcnt(4)); tile 2 stays in flight
    STG_A(0, 0); STG_A(0, 1); STG_B(0, 0); STG_B(0, 1);
    STG_A(1, 0); STG_A(1, 1); STG_B(1, 0); STG_B(1, 1);
    STG_A(2, 0); STG_A(2, 1); STG_B(2, 0); STG_B(2, 1);
    asm volatile("s_waitcnt vmcnt(4)\n\ts_barrier" ::: "memory");

    f32x4 acc[8][4] = {};
    short8 aC[8], aN[8];
    #pragma unroll
    for (int rt = 0; rt < 8; ++rt) aC[rt] = *(const short8*)(lds + arow + rt * 512);  // tile 0

#define TILE_BODY(T_, AC_, AN_) do {                                                   \
    const u16* buf  = lds + ((T_) & 3) * 8192;                                         \
    const u16* bufn = lds + (((T_) + 1) & 3) * 8192;                                   \
    if ((T_) + 3 < NT) { STG_A((T_) + 3, 0); STG_A((T_) + 3, 1); }                     \
    short8 bfr[4];                                                                     \
    _Pragma("unroll")                                                                  \
    for (int ct = 0; ct < 4; ++ct) bfr[ct] = *(const short8*)(buf + brow + ct * 512);  \
    _Pragma("unroll")                                                                  \
    for (int rt = 0; rt < 4; ++rt) AN_[rt] = *(const short8*)(bufn + arow + rt * 512); \
    __builtin_amdgcn_s_setprio(1);                                                     \
    _Pragma("unroll")                                                                  \
    for (int rt = 0; rt < 4; ++rt)                                                     \
        _Pragma("unroll")                                                              \
        for (int ct = 0; ct < 4; ++ct)                                                 \
            acc[rt][ct] = __builtin_amdgcn_mfma_f32_16x16x32_bf16(AC_[rt], bfr[ct], acc[rt][ct], 0, 0, 0); \
    __builtin_amdgcn_s_setprio(0);                                                     \
    if ((T_) + 3 < NT) { STG_B((T_) + 3, 0); STG_B((T_) + 3, 1); }                     \
    _Pragma("unroll")                                                                  \
    for (int rt = 0; rt < 4; ++rt) AN_[rt + 4] = *(const short8*)(bufn + arow + (rt + 4) * 512); \
    __builtin_amdgcn_s_setprio(1);                                                     \
    _Pragma("unroll")                                                                  \
    for (int rt = 0; rt < 4; ++rt)                                                     \
        _Pragma("unroll")                                                              \
        for (int ct = 0; ct < 4; ++ct)                                                 \
            acc[rt + 4][ct] = __builtin_amdgcn_mfma_f32_16x16x32_bf16(AC_[rt + 4], bfr[ct], acc[rt + 4][ct], 0, 0, 0); \
    __builtin_amdgcn_s_setprio(0);                                                     \
    if ((T_) + 3 < NT)      asm volatile("s_waitcnt vmcnt(4)\n\ts_barrier" ::: "memory"); \
    else if ((T_) < NT - 1) asm volatile("s_waitcnt vmcnt(0)\n\ts_barrier" ::: "memory"); \
} while (0)

    for (int t = 0; t < NT; t += 2) {
        TILE_BODY(t, aC, aN);
        TILE_BODY(t + 1, aN, aC);
    }
#undef TILE_BODY
#undef STG_A
#undef STG_B

    __syncthreads();   // safe drain before LDS reuse by epilogue
    if (EPI) {
        // LDS-bounce: per wave [64][80] region (stride 80 u16 = conflict-free readback:
        // granule = (2*row + lane&7) % 8 distinct per octet), two 64-row passes.
        u16* Cw = lds + wid * 5120;
        #pragma unroll
        for (int pass = 0; pass < 2; ++pass) {
            #pragma unroll
            for (int rt = 0; rt < 4; ++rt)
                #pragma unroll
                for (int ct = 0; ct < 4; ++ct)
                    #pragma unroll
                    for (int j = 0; j < 4; ++j) {
                        int row = rt * 16 + (lane >> 4) * 4 + j;
                        int col = ct * 16 + (lane & 15);
                        float v = acc[pass * 4 + rt][ct][j];
                        if (n0 + wc * 64 + col >= og_start) v = 1.0f / (1.0f + expf(-v));
                        Cw[row * 80 + col] = f2bf(v);
                    }
            #pragma unroll
            for (int it = 0; it < 8; ++it) {
                int row = it * 8 + (lane >> 3);
                int c8 = (lane & 7) * 8;
                uint4 val = *reinterpret_cast<const uint4*>(&Cw[row * 80 + c8]);
                *reinterpret_cast<uint4*>((u16*)Cout +
                    (size_t)(m0 + wr * 128 + pass * 64 + row) * ldc + n0 + wc * 64 + c8) = val;
            }
        }
    } else {
        #pragma unroll
        for (int rt = 0; rt < 8; ++rt)
            #pragma unroll
            for (int ct = 0; ct < 4; ++ct)
                #pragma unroll
                for (int j = 0; j < 4; ++j) {
                    int m = m0 + wr * 128 + rt * 16 + (lane >> 4) * 4 + j;
                    int n = n0 + wc * 64 + ct * 16 + (lane & 15);
                    ((float*)Cout)[(size_t)m * ldc + n] = acc[rt][ct][j];
                }
    }
}

// ---------- 128x128 bf16 MFMA GEMM, m97-style (kept for the final f32 GEMM) ----------
template <int EPI>
__global__ __launch_bounds__(256) void gemm_glds(const u16* __restrict__ A, int lda,
                                                 const u16* __restrict__ B, int ldb,
                                                 void* __restrict__ Cout, int ldc,
                                                 int K, int og_start) {
    __shared__ u16 smem[18432];
    u16* As = smem;
    u16* Bs = smem + 4096;
    const int tid = threadIdx.x;
    const int lane = tid & 63, wave = tid >> 6;
    const int m0 = blockIdx.y * 128, n0 = blockIdx.x * 128;
    const int m_off = (wave & 1) * 64, n_off = (wave >> 1) * 64;
    const int r = tid >> 2, kg = (tid & 3) * 8;
    f32x4 acc[4][4] = {};
    for (int k0 = 0; k0 < K; k0 += 32) {
        #pragma unroll
        for (int i = 0; i < 2; ++i) {
            int row = i * 64 + r;
            gload16(A + (size_t)(m0 + row) * lda + k0 + kg, As + (i * 256 + (tid & 192)) * 8);
            gload16(B + (size_t)(n0 + row) * ldb + k0 + kg, Bs + (i * 256 + (tid & 192)) * 8);
        }
        __syncthreads();
        short8 a[4], b[4];
        #pragma unroll
        for (int rt = 0; rt < 4; ++rt)
            a[rt] = *reinterpret_cast<const short8*>(&As[(m_off + rt * 16 + (lane & 15)) * 32 + (lane >> 4) * 8]);
        #pragma unroll
        for (int ct = 0; ct < 4; ++ct)
            b[ct] = *reinterpret_cast<const short8*>(&Bs[(n_off + ct * 16 + (lane & 15)) * 32 + (lane >> 4) * 8]);
        #pragma unroll
        for (int rt = 0; rt < 4; ++rt)
            #pragma unroll
            for (int ct = 0; ct < 4; ++ct)
                acc[rt][ct] = __builtin_amdgcn_mfma_f32_16x16x32_bf16(a[rt], b[ct], acc[rt][ct], 0, 0, 0);
        __syncthreads();
    }
    if (EPI) {
        u16* Cw = smem + wave * 4608;
        #pragma unroll
        for (int rt = 0; rt < 4; ++rt)
            #pragma unroll
            for (int ct = 0; ct < 4; ++ct)
                #pragma unroll
                for (int j = 0; j < 4; ++j) {
                    int row = rt * 16 + (lane >> 4) * 4 + j;
                    int col = ct * 16 + (lane & 15);
                    int n = n0 + n_off + col;
                    float v = acc[rt][ct][j];
                    if (n >= og_start) v = 1.0f / (1.0f + expf(-v));
                    Cw[row * 72 + col] = f2bf(v);
                }
        #pragma unroll
        for (int it = 0; it < 8; ++it) {
            int row = it * 8 + (lane >> 3);
            int c8 = (lane & 7) * 8;
            uint4 val = *reinterpret_cast<const uint4*>(&Cw[row * 72 + c8]);
            *reinterpret_cast<uint4*>((u16*)Cout + (size_t)(m0 + m_off + row) * ldc + n0 + n_off + c8) = val;
        }
    } else {
        #pragma unroll
        for (int rt = 0; rt < 4; ++rt)
            #pragma unroll
            for (int ct = 0; ct < 4; ++ct)
                #pragma unroll
                for (int j = 0; j < 4; ++j) {
                    int m = m0 + m_off + rt * 16 + (lane >> 4) * 4 + j;
                    int n = n0 + n_off + ct * 16 + (lane & 15);
                    ((float*)Cout)[(size_t)m * ldc + n] = acc[rt][ct][j];
                }
    }
}

// ---------- R1: per-chunk U^T = (v .* w)^T-layout MFMA ----------
// LDS transposes use an s-OCTET XOR swizzle (oct ^= (row>>3)&7) on both write & read:
// writes go 32-way -> 4-way bank conflict; b128 reads stay conflict-free
// (granule = row&7 + const within each lane-octet). Stride stays 72 (b128-aligned).
__global__ __launch_bounds__(256) void r1_kernel(const u16* __restrict__ proj,
                                                 const float* __restrict__ l2a,
                                                 u16* __restrict__ U,
                                                 float* __restrict__ Gc) {
    __shared__ u16 kT[128 * 72];   // kT[r][s-swz]
    __shared__ u16 vT[256 * 72];   // vT[c][s-swz], scaled by w_s
    __shared__ float Wsh[64];
    int bid = blockIdx.x;
    int c = bid & 63, bh = bid >> 6;
    int b = bh >> 3, h = bh & 7;
    int c0 = c * CHUNK;
    int tid = threadIdx.x, lane = tid & 63, wave = tid >> 6;
    size_t rowbase = (size_t)b * SEQ + c0;
    if (wave == 0) {
        float L = l2a[(rowbase + lane) * NH + h];
        #pragma unroll
        for (int d = 1; d < 64; d <<= 1) {
            float u = __shfl_up(L, d, 64);
            if (lane >= d) L += u;
        }
        float Lend = __shfl(L, 63, 64);
        Wsh[lane] = exp2f(Lend - L);
        if (lane == 0) Gc[bh * NCHUNK + c] = exp2f(Lend);
    }
    __syncthreads();
    // stage kT: element (r+i, s) at (r+i)*72 + swz(s, (r+i)>>3); (r+i)>>3 = cid&15 -> &7 = cid&7
    #pragma unroll
    for (int j = 0; j < 4; ++j) {
        int cid = tid + j * 256;
        int s = cid >> 4, r = (cid & 15) * 8;
        int ko = (s & 7) | ((((s >> 3) ^ cid) & 7) << 3);
        uint4 v = *(const uint4*)(proj + (rowbase + s) * NPROJ + 1024 + h * DKH + r);
        u16 e[8]; *(uint4*)e = v;
        #pragma unroll
        for (int i = 0; i < 8; ++i) kT[(r + i) * 72 + ko] = e[i];
    }
    // stage vT scaled by w_s: (cc+i)>>3 = cid&31 -> &7 = cid&7
    #pragma unroll
    for (int j = 0; j < 8; ++j) {
        int cid = tid + j * 256;
        int s = cid >> 5, cc = (cid & 31) * 8;
        float w = Wsh[s];
        int vo = (s & 7) | ((((s >> 3) ^ cid) & 7) << 3);
        uint4 v = *(const uint4*)(proj + (rowbase + s) * NPROJ + 2048 + h * DVH + cc);
        u16 e[8]; *(uint4*)e = v;
        #pragma unroll
        for (int i = 0; i < 8; ++i) vT[(cc + i) * 72 + vo] = f2bf(bf2f(e[i]) * w);
    }
    __syncthreads();
    // U^T[c][r] = sum_s (w_s v[s][c]) k[s][r]; wave owns c-rows [64*wave, +64)
    short8 afr[4][2];
    #pragma unroll
    for (int rt = 0; rt < 4; ++rt)
        #pragma unroll
        for (int kk = 0; kk < 2; ++kk) {
            int cA = wave * 64 + rt * 16 + (lane & 15);
            int op = ((kk * 4 + (lane >> 4)) ^ ((cA >> 3) & 7)) * 8;
            afr[rt][kk] = *reinterpret_cast<const short8*>(&vT[cA * 72 + op]);
        }
    size_t ubase = (size_t)(bh * NCHUNK + c) * (DVH * DKH);
    #pragma unroll
    for (int ct = 0; ct < 8; ++ct) {
        f32x4 acc[4] = {};
        #pragma unroll
        for (int kk = 0; kk < 2; ++kk) {
            int rB = ct * 16 + (lane & 15);
            int op = ((kk * 4 + (lane >> 4)) ^ ((rB >> 3) & 7)) * 8;
            short8 bfr = *reinterpret_cast<const short8*>(&kT[rB * 72 + op]);
            #pragma unroll
            for (int rt = 0; rt < 4; ++rt)
                acc[rt] = __builtin_amdgcn_mfma_f32_16x16x32_bf16(afr[rt][kk], bfr, acc[rt], 0, 0, 0);
        }
        #pragma unroll
        for (int rt = 0; rt < 4; ++rt)
            #pragma unroll
            for (int j = 0; j < 4; ++j) {
                int ccr = wave * 64 + rt * 16 + (lane >> 4) * 4 + j;
                int rr = ct * 16 + (lane & 15);
                U[ubase + (size_t)ccr * DKH + rr] = f2bf(acc[rt][j]);
            }
    }
}

// ---------- R2: sequential scan over chunks (in-place U -> S_prefix) ----------
__global__ __launch_bounds__(256) void r2_kernel(u16* __restrict__ U, const float* __restrict__ Gc) {
    int bh = blockIdx.x >> 5;
    int e0 = ((blockIdx.x & 31) * 256 + threadIdx.x) * 4;
    const float* g = Gc + bh * NCHUNK;
    size_t base = (size_t)bh * NCHUNK * (DVH * DKH) + e0;
    float s0 = 0.f, s1 = 0.f, s2 = 0.f, s3 = 0.f;
    for (int c = 0; c < NCHUNK; ++c) {
        u16* p = U + base + (size_t)c * (DVH * DKH);
        uint2 u = *(const uint2*)p;
        u16 e[4]; *(uint2*)e = u;
        u16 o[4] = { f2bf(s0), f2bf(s1), f2bf(s2), f2bf(s3) };
        *(uint2*)p = *(const uint2*)o;
        float G = g[c];
        s0 = G * s0 + bf2f(e[0]);
        s1 = G * s1 + bf2f(e[1]);
        s2 = G * s2 + bf2f(e[2]);
        s3 = G * s3 + bf2f(e[3]);
    }
}

// ---------- R3: chunk outputs (inter + intra) fused with og multiply ----------
__global__ __launch_bounds__(256) void r3_kernel(const u16* __restrict__ proj,
                                                 const u16* __restrict__ Sp,
                                                 const float* __restrict__ l2a,
                                                 u16* __restrict__ z) {
    __shared__ u16 vT[256 * 72];   // vT[c][s-swz]
    __shared__ u16 P[64 * 72];     // P[t][s] decayed, bf16 (write pattern already 2-way: OK)
    __shared__ float Lsh[64];
    int bid = blockIdx.x;
    int c = bid & 63, bh = bid >> 6;
    int b = bh >> 3, h = bh & 7;
    int c0 = c * CHUNK;
    int tid = threadIdx.x, lane = tid & 63, wave = tid >> 6;
    size_t rowbase = (size_t)b * SEQ + c0;
    if (wave == 0) {
        float L = l2a[(rowbase + lane) * NH + h];
        #pragma unroll
        for (int d = 1; d < 64; d <<= 1) {
            float u = __shfl_up(L, d, 64);
            if (lane >= d) L += u;
        }
        Lsh[lane] = L;
    }
    // stage vT (unscaled), octet-swizzled like r1
    #pragma unroll
    for (int j = 0; j < 8; ++j) {
        int cid = tid + j * 256;
        int s = cid >> 5, cc = (cid & 31) * 8;
        int vo = (s & 7) | ((((s >> 3) ^ cid) & 7) << 3);
        uint4 v = *(const uint4*)(proj + (rowbase + s) * NPROJ + 2048 + h * DVH + cc);
        u16 e[8]; *(uint4*)e = v;
        #pragma unroll
        for (int i = 0; i < 8; ++i) vT[(cc + i) * 72 + vo] = e[i];
    }
    __syncthreads();
    // phase 1a: P strip rows [16*wave, +16): P[t][s] = (q k^T)[t][s] * exp2(L_t - L_s), causal
    {
        f32x4 pacc[4] = {};
        #pragma unroll
        for (int kk = 0; kk < 4; ++kk) {
            short8 a = *reinterpret_cast<const short8*>(
                proj + (rowbase + wave * 16 + (lane & 15)) * NPROJ + h * DKH + kk * 32 + (lane >> 4) * 8);
            #pragma unroll
            for (int st = 0; st < 4; ++st) {
                short8 bb = *reinterpret_cast<const short8*>(
                    proj + (rowbase + st * 16 + (lane & 15)) * NPROJ + 1024 + h * DKH + kk * 32 + (lane >> 4) * 8);
                pacc[st] = __builtin_amdgcn_mfma_f32_16x16x32_bf16(a, bb, pacc[st], 0, 0, 0);
            }
        }
        #pragma unroll
        for (int st = 0; st < 4; ++st)
            #pragma unroll
            for (int j = 0; j < 4; ++j) {
                int t = wave * 16 + (lane >> 4) * 4 + j;
                int s = st * 16 + (lane & 15);
                float val = pacc[st][j];
                val = (s <= t) ? val * exp2f(Lsh[t] - Lsh[s]) : 0.f;
                P[t * 72 + s] = f2bf(val);
            }
    }
    // phase 1b: inter = q @ S_prefix (wave owns output cols [64*wave, +64))
    f32x4 acc[4][4] = {};
    size_t spbase = (size_t)(bh * NCHUNK + c) * (DVH * DKH);
    #pragma unroll
    for (int kk = 0; kk < 4; ++kk) {
        short8 a[4];
        #pragma unroll
        for (int rt = 0; rt < 4; ++rt)
            a[rt] = *reinterpret_cast<const short8*>(
                proj + (rowbase + rt * 16 + (lane & 15)) * NPROJ + h * DKH + kk * 32 + (lane >> 4) * 8);
        #pragma unroll
        for (int ct = 0; ct < 4; ++ct) {
            short8 bb = *reinterpret_cast<const short8*>(
                Sp + spbase + (size_t)(wave * 64 + ct * 16 + (lane & 15)) * DKH + kk * 32 + (lane >> 4) * 8);
            #pragma unroll
            for (int rt = 0; rt < 4; ++rt)
                acc[rt][ct] = __builtin_amdgcn_mfma_f32_16x16x32_bf16(a[rt], bb, acc[rt][ct], 0, 0, 0);
        }
    }
    #pragma unroll
    for (int rt = 0; rt < 4; ++rt)
        #pragma unroll
        for (int j = 0; j < 4; ++j) {
            float at = exp2f(Lsh[rt * 16 + (lane >> 4) * 4 + j]);
            #pragma unroll
            for (int ct = 0; ct < 4; ++ct) acc[rt][ct][j] *= at;
        }
    __syncthreads();
    // phase 2: intra = P @ v
    #pragma unroll
    for (int kk = 0; kk < 2; ++kk) {
        short8 pa[4];
        #pragma unroll
        for (int rt = 0; rt < 4; ++rt)
            pa[rt] = *reinterpret_cast<const short8*>(&P[(rt * 16 + (lane & 15)) * 72 + kk * 32 + (lane >> 4) * 8]);
        #pragma unroll
        for (int ct = 0; ct < 4; ++ct) {
            int cV = wave * 64 + ct * 16 + (lane & 15);
            int op = ((kk * 4 + (lane >> 4)) ^ ((cV >> 3) & 7)) * 8;
            short8 vb = *reinterpret_cast<const short8*>(&vT[cV * 72 + op]);
            #pragma unroll
            for (int rt = 0; rt < 4; ++rt)
                acc[rt][ct] = __builtin_amdgcn_mfma_f32_16x16x32_bf16(pa[rt], vb, acc[rt][ct], 0, 0, 0);
        }
    }
    // phase 3: z = o * og
    #pragma unroll
    for (int rt = 0; rt < 4; ++rt)
        #pragma unroll
        for (int ct = 0; ct < 4; ++ct)
            #pragma unroll
            for (int j = 0; j < 4; ++j) {
                int t = rt * 16 + (lane >> 4) * 4 + j;
                int cc = wave * 64 + ct * 16 + (lane & 15);
                float og = bf2f(proj[(rowbase + t) * NPROJ + 4096 + h * DVH + cc]);
                float v = acc[rt][ct][j] * og;
                z[(rowbase + t) * (NH * DVH) + h * DVH + cc] = f2bf(v);
            }
}

extern "C" void kernel_launch(void* const* d_in, const int* in_sizes, int n_in,
                              void* d_out, int out_size, void* d_ws, size_t ws_size,
                              hipStream_t stream) {
    const float* x   = (const float*)d_in[0];
    const float* Wq  = (const float*)d_in[1];
    const float* Wk  = (const float*)d_in[2];
    const float* Wv  = (const float*)d_in[3];
    const float* Wo  = (const float*)d_in[4];
    const float* Wg  = (const float*)d_in[5];
    const float* bg  = (const float*)d_in[6];
    const float* Wog = (const float*)d_in[7];
    float* out = (float*)d_out;
    char* ws = (char*)d_ws;

    u16*   xb   = (u16*)(ws + OFF_XB);
    u16*   wcat = (u16*)(ws + OFF_WCAT);
    u16*   wot  = (u16*)(ws + OFF_WOT);
    u16*   proj = (u16*)(ws + OFF_PROJ);
    float* l2a  = (float*)(ws + OFF_L2A);
    float* gc   = (float*)(ws + OFF_GC);
    u16*   U    = (u16*)(ws + OFF_U);
    u16*   z    = (u16*)(ws + OFF_Z);

    cvt_x_kernel<<<8192, 256, 0, stream>>>(x, xb);
    dim3 tb(32, 8);
    transpose_w<<<dim3(32, 32), tb, 0, stream>>>(Wq,  1024, 1024, wcat,               1.0f);
    transpose_w<<<dim3(32, 32), tb, 0, stream>>>(Wk,  1024, 1024, wcat + 1024 * 1024, 0.08838834764831845f); // fold DK^-0.5
    transpose_w<<<dim3(64, 32), tb, 0, stream>>>(Wv,  2048, 1024, wcat + 2048 * 1024, 1.0f);
    transpose_w<<<dim3(64, 32), tb, 0, stream>>>(Wog, 2048, 1024, wcat + 4096 * 1024, 1.0f);
    transpose_w<<<dim3(32, 64), tb, 0, stream>>>(Wo,  1024, 2048, wot,                1.0f);
    alpha_kernel<<<8192, 256, 0, stream>>>(x, Wg, bg, l2a);
    // projections: [8192,1024] @ [6144,1024]^T -> proj bf16 (sigmoid on og cols)
    // grid 32x24=768 tiles (768 % 8 == 0 -> bijective XCD swizzle)
    gemm256<1><<<768, 512, 0, stream>>>(xb, 1024, wcat, 1024, proj, NPROJ, 1024, 24, 4096);
    r1_kernel<<<BATCH * NH * NCHUNK, 256, 0, stream>>>(proj, l2a, U, gc);
    r2_kernel<<<512, 256, 0, stream>>>(U, gc);
    r3_kernel<<<BATCH * NH * NCHUNK, 256, 0, stream>>>(proj, U, l2a, z);
    // final: [8192,2048] @ [1024,2048]^T -> d_out f32
    gemm_glds<0><<<dim3(8, 64), 256, 0, stream>>>(z, 2048, wot, 2048, out, 1024, 2048, 1 << 30);
}